// Round 2
// baseline (733.681 us; speedup 1.0000x reference)
//
#include <hip/hip_runtime.h>
#include <stdint.h>

typedef uint16_t u16;
typedef uint32_t u32;

typedef __attribute__((ext_vector_type(8))) short bf16x8;
typedef __attribute__((ext_vector_type(4))) float f32x4;

#define S_LEN 4096
#define HDIM  256
#define MROWS 16384
#define FFDIM 1024

__device__ __forceinline__ float bf2f(u16 u) { return __uint_as_float(((u32)u) << 16); }
__device__ __forceinline__ u16 f2bf(float f) {
  u32 x = __float_as_uint(f);
  return (u16)((x + 0x7fffu + ((x >> 16) & 1u)) >> 16);
}
__device__ __forceinline__ float gelu_f(float x) {
  return 0.5f * x * (1.0f + erff(x * 0.7071067811865475f));
}

// ---------------- transpose+cast (f32 [K][N] -> bf16 [N][K]) ----------------
__global__ __launch_bounds__(256) void ktranspose(const float* __restrict__ in, u16* __restrict__ out,
                                                  int K, int N) {
  __shared__ u16 t[32][33];
  const int k0 = blockIdx.x * 32, n0 = blockIdx.y * 32;
  const int tx = threadIdx.x, ty = threadIdx.y;
#pragma unroll
  for (int i = ty; i < 32; i += 8) t[i][tx] = f2bf(in[(long)(k0 + i) * N + (n0 + tx)]);
  __syncthreads();
#pragma unroll
  for (int i = ty; i < 32; i += 8) out[(long)(n0 + i) * K + (k0 + tx)] = t[tx][i];
}

// ---------------- layernorm (ddof=1, eps added to std) ----------------
// in: f32, OUTBF: 1 -> bf16 out, 0 -> f32 out
template <int OUTBF>
__global__ __launch_bounds__(256) void ln_kernel(const float* __restrict__ inv, void* __restrict__ outv,
                                                 const float* __restrict__ g, const float* __restrict__ bsh) {
  const int tid = threadIdx.x;
  const int lane = tid & 63;
  const long row = (long)blockIdx.x * 4 + (tid >> 6);
  const int c0 = lane * 4;
  float v[4];
  float4 f = *(const float4*)(inv + row * HDIM + c0);
  v[0] = f.x; v[1] = f.y; v[2] = f.z; v[3] = f.w;
  float s = v[0] + v[1] + v[2] + v[3];
#pragma unroll
  for (int o = 32; o > 0; o >>= 1) s += __shfl_xor(s, o);
  const float mean = s * (1.0f / 256.0f);
  float ss = 0.f;
#pragma unroll
  for (int j = 0; j < 4; ++j) { float d = v[j] - mean; ss += d * d; }
#pragma unroll
  for (int o = 32; o > 0; o >>= 1) ss += __shfl_xor(ss, o);
  const float inv_ = 1.0f / (sqrtf(ss * (1.0f / 255.0f)) + 1e-9f);
  float y[4];
#pragma unroll
  for (int j = 0; j < 4; ++j) y[j] = g[c0 + j] * (v[j] - mean) * inv_ + bsh[c0 + j];
  if (OUTBF) {
    uint2 o_;
    o_.x = (u32)f2bf(y[0]) | ((u32)f2bf(y[1]) << 16);
    o_.y = (u32)f2bf(y[2]) | ((u32)f2bf(y[3]) << 16);
    *(uint2*)((u16*)outv + row * HDIM + c0) = o_;
  } else {
    float4 o_; o_.x = y[0]; o_.y = y[1]; o_.z = y[2]; o_.w = y[3];
    *(float4*)((float*)outv + row * HDIM + c0) = o_;
  }
}

// ---------------- depthwise 9-tap (pad 4/4) + gelu -> hmid (f32) ----------------
__global__ __launch_bounds__(256) void dwconv_kernel(const float* __restrict__ xn, float* __restrict__ hmid,
                                                     const float* __restrict__ dw_w, const float* __restrict__ dw_b) {
  const int tid = threadIdx.x;
  const int lane = tid & 63;
  const long row = (long)blockIdx.x * 4 + (tid >> 6);
  const int sl = (int)(row & (S_LEN - 1));
  const float b0 = dw_b[0];
  float a0 = b0, a1 = b0, a2 = b0, a3 = b0;
#pragma unroll
  for (int t = 0; t < 9; ++t) {
    const int s2 = sl + t - 4;
    if (s2 >= 0 && s2 < S_LEN) {
      const float w = dw_w[t];
      float4 xv = *(const float4*)(xn + (row + t - 4) * HDIM + lane * 4);
      a0 = fmaf(w, xv.x, a0); a1 = fmaf(w, xv.y, a1);
      a2 = fmaf(w, xv.z, a2); a3 = fmaf(w, xv.w, a3);
    }
  }
  float4 o_;
  o_.x = gelu_f(a0); o_.y = gelu_f(a1); o_.z = gelu_f(a2); o_.w = gelu_f(a3);
  *(float4*)(hmid + row * HDIM + lane * 4) = o_;
}

// ---------------- unified MFMA GEMM ----------------
// ASRC: 0 = fp32 source with gelu(a*pw+pb) transform; 1 = bf16 source plain
// EPI : 0 = bf16 store *oscale (qkv); 1 = fp32 store + f32 residual (Wo)
//       2 = bf16 store gelu(acc+bias) (conv1); 3 = fp32 partial store (conv2 split-K)
template <int ASRC, int EPI>
__global__ __launch_bounds__(256) void gemm_kernel(
    const void* __restrict__ Av, const u16* __restrict__ BT, void* __restrict__ Outv,
    const float* __restrict__ bias, const float* __restrict__ residv,
    int KW, int BPITCH, int ntaps, int tap_off0, int tap_stride, int ubase_mult,
    float oscale, const float* __restrict__ pw_w, const float* __restrict__ pw_b, int pwidx,
    int N, long out_z_off) {
  __shared__ __align__(16) u16 As[128 * 72];
  __shared__ __align__(16) u16 Bs[128 * 72];
  const int tid = threadIdx.x;
  const int lane = tid & 63;
  const int wid = tid >> 6;
  const int wm = (wid & 1) * 64;
  const int wn = (wid >> 1) * 64;
  const int fm = lane & 15;
  const int fq = lane >> 4;
  const int t0 = blockIdx.x * 128;
  const int n0 = blockIdx.y * 128;
  const int ubase = blockIdx.z * ubase_mult;

  float pwv = 0.f, pbv = 0.f;
  if (ASRC == 0) { pwv = pw_w[pwidx]; pbv = pw_b[pwidx]; }

  f32x4 acc[4][4];
#pragma unroll
  for (int a = 0; a < 4; ++a)
#pragma unroll
    for (int b = 0; b < 4; ++b) acc[a][b] = (f32x4){0.f, 0.f, 0.f, 0.f};

  const int sr = tid >> 3;
  const int sc = (tid & 7) * 8;

  for (int u = 0; u < ntaps; ++u) {
    const int ug = ubase + u;
    const int toff = tap_off0 + ug * tap_stride;
    const long bcolbase = (long)ug * KW;
    for (int k0 = 0; k0 < KW; k0 += 64) {
      // stage A (128 x 64 bf16), causal zero-mask per batch
#pragma unroll
      for (int p = 0; p < 4; ++p) {
        const int row = p * 32 + sr;
        const int grow = t0 + row;
        const int sl = grow & (S_LEN - 1);
        const int ssrc = sl + toff;
        uint4 pk = {0u, 0u, 0u, 0u};
        if (ssrc >= 0 && ssrc < S_LEN) {
          const long arow = (long)grow + toff;
          if (ASRC == 0) {
            const float* ap = (const float*)Av + arow * KW + k0 + sc;
            float4 x0 = *(const float4*)ap;
            float4 x1 = *(const float4*)(ap + 4);
            float tv[8] = {x0.x, x0.y, x0.z, x0.w, x1.x, x1.y, x1.z, x1.w};
#pragma unroll
            for (int e = 0; e < 8; ++e) tv[e] = gelu_f(fmaf(tv[e], pwv, pbv));
            pk.x = (u32)f2bf(tv[0]) | ((u32)f2bf(tv[1]) << 16);
            pk.y = (u32)f2bf(tv[2]) | ((u32)f2bf(tv[3]) << 16);
            pk.z = (u32)f2bf(tv[4]) | ((u32)f2bf(tv[5]) << 16);
            pk.w = (u32)f2bf(tv[6]) | ((u32)f2bf(tv[7]) << 16);
          } else {
            pk = *(const uint4*)((const u16*)Av + arow * KW + k0 + sc);
          }
        }
        *(uint4*)&As[row * 72 + sc] = pk;
      }
      // stage B^T (pre-transposed weights: [N][K], row-contiguous in k)
#pragma unroll
      for (int p = 0; p < 4; ++p) {
        const int row = p * 32 + sr;
        uint4 pk = *(const uint4*)(BT + (long)(n0 + row) * BPITCH + bcolbase + k0 + sc);
        *(uint4*)&Bs[row * 72 + sc] = pk;
      }
      __syncthreads();
#pragma unroll
      for (int kk = 0; kk < 64; kk += 32) {
        bf16x8 af[4], bfv[4];
#pragma unroll
        for (int t = 0; t < 4; ++t) af[t] = *(const bf16x8*)&As[(wm + t * 16 + fm) * 72 + kk + fq * 8];
#pragma unroll
        for (int t = 0; t < 4; ++t) bfv[t] = *(const bf16x8*)&Bs[(wn + t * 16 + fm) * 72 + kk + fq * 8];
#pragma unroll
        for (int mi = 0; mi < 4; ++mi)
#pragma unroll
          for (int ni = 0; ni < 4; ++ni)
            acc[mi][ni] = __builtin_amdgcn_mfma_f32_16x16x32_bf16(af[mi], bfv[ni], acc[mi][ni], 0, 0, 0);
      }
      __syncthreads();
    }
  }

  // epilogue: C/D layout col = lane&15, row = (lane>>4)*4 + reg
#pragma unroll
  for (int mi = 0; mi < 4; ++mi)
#pragma unroll
    for (int ni = 0; ni < 4; ++ni)
#pragma unroll
      for (int r = 0; r < 4; ++r) {
        const long trow = t0 + wm + mi * 16 + fq * 4 + r;
        const int col = n0 + wn + ni * 16 + fm;
        const float cv = acc[mi][ni][r];
        if (EPI == 0) {
          ((u16*)Outv)[trow * N + col] = f2bf(cv * oscale);
        } else if (EPI == 1) {
          ((float*)Outv)[trow * N + col] = cv + residv[trow * N + col];
        } else if (EPI == 2) {
          ((u16*)Outv)[trow * N + col] = f2bf(gelu_f(cv + bias[col]));
        } else {
          (((float*)Outv) + (long)blockIdx.z * out_z_off)[trow * N + col] = cv;
        }
      }
}

// ---------------- sliding-window attention (VALU online softmax) ----------------
__global__ __launch_bounds__(256) void attn_kernel(const u16* __restrict__ Q, const u16* __restrict__ K,
                                                   const u16* __restrict__ V, const float* __restrict__ rel,
                                                   u16* __restrict__ CTX) {
  __shared__ __align__(16) u16 ks[384 * 36];
  __shared__ __align__(16) u16 vs[384 * 36];
  __shared__ float bias_s[257];
  const int c = blockIdx.x, h = blockIdx.y, b = blockIdx.z;
  const int tid = threadIdx.x;
  const int i = tid & 127, phi = tid >> 7;
  const int j0 = c * 128 - 128;
  const long hb = ((long)b * S_LEN) * HDIM + h * 32;

  for (int idx = tid; idx < 384 * 4; idx += 256) {
    const int jj = idx >> 2, seg = (idx & 3) * 8;
    const int j = j0 + jj;
    uint4 ku = {0u, 0u, 0u, 0u}, vu = {0u, 0u, 0u, 0u};
    if (j >= 0 && j < S_LEN) {
      ku = *(const uint4*)(K + hb + (long)j * HDIM + seg);
      vu = *(const uint4*)(V + hb + (long)j * HDIM + seg);
    }
    uint2 a, bb;
    a.x = ku.x; a.y = ku.y; bb.x = ku.z; bb.y = ku.w;
    *(uint2*)&ks[jj * 36 + seg] = a;
    *(uint2*)&ks[jj * 36 + seg + 4] = bb;
    a.x = vu.x; a.y = vu.y; bb.x = vu.z; bb.y = vu.w;
    *(uint2*)&vs[jj * 36 + seg] = a;
    *(uint2*)&vs[jj * 36 + seg + 4] = bb;
  }
  for (int idx = tid; idx < 257; idx += 256) bias_s[idx] = rel[idx];
  __syncthreads();

  const int s = c * 128 + i;
  float qr[32];
  {
    const uint4* qp = (const uint4*)(Q + hb + (long)s * HDIM);
#pragma unroll
    for (int w = 0; w < 4; ++w) {
      uint4 u = qp[w];
      u32 uu[4] = {u.x, u.y, u.z, u.w};
#pragma unroll
      for (int e = 0; e < 4; ++e) {
        qr[w * 8 + e * 2] = __uint_as_float(uu[e] << 16);
        qr[w * 8 + e * 2 + 1] = __uint_as_float(uu[e] & 0xffff0000u);
      }
    }
  }
  const int rlo = (128 - s) > 0 ? (128 - s) : 0;
  const int rhi = (4223 - s) < 256 ? (4223 - s) : 256;
  float m = -1e30f, l = 0.f;
  float acc[32];
#pragma unroll
  for (int d = 0; d < 32; ++d) acc[d] = 0.f;

  for (int r = rlo + phi; r <= rhi; r += 2) {
    const u16* kr = &ks[(i + r) * 36];
    float d0 = 0.f, d1 = 0.f, d2 = 0.f, d3 = 0.f;
#pragma unroll
    for (int d = 0; d < 32; d += 8) {
      const u32 p0 = *(const u32*)(kr + d);
      const u32 p1 = *(const u32*)(kr + d + 2);
      const u32 p2 = *(const u32*)(kr + d + 4);
      const u32 p3 = *(const u32*)(kr + d + 6);
      d0 = fmaf(qr[d], __uint_as_float(p0 << 16), d0);
      d0 = fmaf(qr[d + 1], __uint_as_float(p0 & 0xffff0000u), d0);
      d1 = fmaf(qr[d + 2], __uint_as_float(p1 << 16), d1);
      d1 = fmaf(qr[d + 3], __uint_as_float(p1 & 0xffff0000u), d1);
      d2 = fmaf(qr[d + 4], __uint_as_float(p2 << 16), d2);
      d2 = fmaf(qr[d + 5], __uint_as_float(p2 & 0xffff0000u), d2);
      d3 = fmaf(qr[d + 6], __uint_as_float(p3 << 16), d3);
      d3 = fmaf(qr[d + 7], __uint_as_float(p3 & 0xffff0000u), d3);
    }
    const float sc_ = (d0 + d1) + (d2 + d3) + bias_s[r];
    float e;
    if (sc_ > m) {
      const float scale = __expf(m - sc_);
      l *= scale;
#pragma unroll
      for (int d = 0; d < 32; ++d) acc[d] *= scale;
      m = sc_;
      e = 1.f;
    } else {
      e = __expf(sc_ - m);
    }
    l += e;
    const u16* vr = &vs[(i + r) * 36];
#pragma unroll
    for (int d = 0; d < 32; d += 2) {
      const u32 p = *(const u32*)(vr + d);
      acc[d] = fmaf(e, __uint_as_float(p << 16), acc[d]);
      acc[d + 1] = fmaf(e, __uint_as_float(p & 0xffff0000u), acc[d + 1]);
    }
  }

  __syncthreads();
  float* scr = (float*)(void*)ks;  // overlay merge scratch on ks (done with it)
  if (phi == 1) {
    float* p = scr + i * 34;
    p[0] = m; p[1] = l;
#pragma unroll
    for (int d = 0; d < 32; ++d) p[2 + d] = acc[d];
  }
  __syncthreads();
  if (phi == 0) {
    const float* p = scr + i * 34;
    const float m1 = p[0], l1 = p[1];
    const float M = fmaxf(m, m1);
    const float a0 = __expf(m - M), a1 = __expf(m1 - M);
    const float inv = 1.0f / (l * a0 + l1 * a1);
    u32 ob[16];
#pragma unroll
    for (int d = 0; d < 32; d += 2) {
      const float o0 = (acc[d] * a0 + p[2 + d] * a1) * inv;
      const float o1 = (acc[d + 1] * a0 + p[2 + d + 1] * a1) * inv;
      ob[d >> 1] = (u32)f2bf(o0) | ((u32)f2bf(o1) << 16);
    }
    uint4* op = (uint4*)(CTX + hb + (long)s * HDIM);
    const uint4* obv = (const uint4*)ob;
    op[0] = obv[0]; op[1] = obv[1]; op[2] = obv[2]; op[3] = obv[3];
  }
}

// ---------------- final: out = x2 + gelu(P0+P1+P2 + b2)  (f32 out) ----------------
__global__ __launch_bounds__(256) void final_kernel(const float* __restrict__ x2, const float* __restrict__ P,
                                                    const float* __restrict__ b2, float* __restrict__ out) {
  const long i4 = ((long)blockIdx.x * 256 + threadIdx.x) * 4;
  const int c0 = (int)(i4 & (HDIM - 1));
  float4 xa = *(const float4*)(x2 + i4);
  float4 p0 = *(const float4*)(P + i4);
  float4 p1 = *(const float4*)(P + 4194304 + i4);
  float4 p2 = *(const float4*)(P + 8388608 + i4);
  const float pv[4] = {p0.x + p1.x + p2.x, p0.y + p1.y + p2.y, p0.z + p1.z + p2.z, p0.w + p1.w + p2.w};
  const float xv[4] = {xa.x, xa.y, xa.z, xa.w};
  float4 o_;
  o_.x = xv[0] + gelu_f(pv[0] + b2[c0 + 0]);
  o_.y = xv[1] + gelu_f(pv[1] + b2[c0 + 1]);
  o_.z = xv[2] + gelu_f(pv[2] + b2[c0 + 2]);
  o_.w = xv[3] + gelu_f(pv[3] + b2[c0 + 3]);
  *(float4*)(out + i4) = o_;
}

extern "C" void kernel_launch(void* const* d_in, const int* in_sizes, int n_in,
                              void* d_out, int out_size, void* d_ws, size_t ws_size,
                              hipStream_t stream) {
  (void)in_sizes; (void)n_in; (void)out_size;
  const float* X    = (const float*)d_in[0];
  const float* dw_w = (const float*)d_in[1];
  const float* dw_b = (const float*)d_in[2];
  const float* pw_w = (const float*)d_in[3];
  const float* pw_b = (const float*)d_in[4];
  const float* Wq   = (const float*)d_in[5];
  const float* Wk   = (const float*)d_in[6];
  const float* Wv   = (const float*)d_in[7];
  const float* Wo   = (const float*)d_in[8];
  const float* rel  = (const float*)d_in[9];
  const float* ln1g = (const float*)d_in[10];
  const float* ln1b = (const float*)d_in[11];
  const float* ln2g = (const float*)d_in[12];
  const float* ln2b = (const float*)d_in[13];
  const float* w1   = (const float*)d_in[14];
  const float* b1   = (const float*)d_in[15];
  const float* w2   = (const float*)d_in[16];
  const float* b2   = (const float*)d_in[17];

  if (ws_size < 119537664) return;  // fail cleanly rather than corrupt

  char* ws = (char*)d_ws;
  u16* WqT = (u16*)(ws + 0);
  u16* WkT = (u16*)(ws + 131072);
  u16* WvT = (u16*)(ws + 262144);
  u16* WoT = (u16*)(ws + 393216);
  u16* W1T = (u16*)(ws + 524288);
  u16* W2T = (u16*)(ws + 524288 + 4718592);
  const size_t R1 = 10485760;  // 10 MB for weights
  float* xn   = (float*)(ws + R1);                          // 16MB, reused as x2
  float* x2   = xn;
  float* hmid = (float*)(ws + R1 + (16ull << 20));          // 16MB, reused as P0 (P contiguous 48MB)
  float* P    = hmid;
  u16* q    = (u16*)(ws + R1 + (32ull << 20));              // 8MB (P1 low)
  u16* k    = (u16*)(ws + R1 + (40ull << 20));              // 8MB (P1 high)
  u16* v    = (u16*)(ws + R1 + (48ull << 20));              // 8MB (P2 low)
  u16* ctx  = (u16*)(ws + R1 + (56ull << 20));              // 8MB (P2 high)
  u16* f1   = (u16*)(ws + R1 + (64ull << 20));              // 32MB
  u16* xn2  = (u16*)(ws + R1 + (96ull << 20));              // 8MB

  dim3 tb(32, 8);
  ktranspose<<<dim3(8, 8), tb, 0, stream>>>(Wq, WqT, 256, 256);
  ktranspose<<<dim3(8, 8), tb, 0, stream>>>(Wk, WkT, 256, 256);
  ktranspose<<<dim3(8, 8), tb, 0, stream>>>(Wv, WvT, 256, 256);
  ktranspose<<<dim3(8, 8), tb, 0, stream>>>(Wo, WoT, 256, 256);
  ktranspose<<<dim3(72, 32), tb, 0, stream>>>(w1, W1T, 2304, 1024);
  ktranspose<<<dim3(288, 8), tb, 0, stream>>>(w2, W2T, 9216, 256);

  ln_kernel<0><<<4096, 256, 0, stream>>>(X, xn, ln1g, ln1b);
  dwconv_kernel<<<4096, 256, 0, stream>>>(xn, hmid, dw_w, dw_b);

  const float qscale = 0.17677669529663687f;  // DH^-0.5
  gemm_kernel<0, 0><<<dim3(128, 2), 256, 0, stream>>>(hmid, WqT, q, nullptr, nullptr,
      256, 256, 1, 0, 0, 0, qscale, pw_w, pw_b, 0, 256, 0);
  gemm_kernel<0, 0><<<dim3(128, 2), 256, 0, stream>>>(hmid, WkT, k, nullptr, nullptr,
      256, 256, 1, 0, 0, 0, 1.0f, pw_w, pw_b, 1, 256, 0);
  gemm_kernel<0, 0><<<dim3(128, 2), 256, 0, stream>>>(hmid, WvT, v, nullptr, nullptr,
      256, 256, 1, 0, 0, 0, 1.0f, pw_w, pw_b, 2, 256, 0);

  attn_kernel<<<dim3(32, 8, 4), 256, 0, stream>>>(q, k, v, rel, ctx);

  gemm_kernel<1, 1><<<dim3(128, 2), 256, 0, stream>>>(ctx, WoT, x2, nullptr, X,
      256, 256, 1, 0, 0, 0, 1.0f, nullptr, nullptr, 0, 256, 0);

  ln_kernel<1><<<4096, 256, 0, stream>>>(x2, xn2, ln2g, ln2b);

  // conv1: K = 9 taps x 256, shifts u-8 (causal), N=1024, gelu+bias epilogue -> f1 (bf16)
  gemm_kernel<1, 2><<<dim3(128, 8), 256, 0, stream>>>(xn2, W1T, f1, b1, nullptr,
      256, 2304, 9, -8, 1, 0, 1.0f, nullptr, nullptr, 0, 1024, 0);

  // conv2: K = 9 taps x 1024, shifts 8u-64, split-K x3 over grid.z -> fp32 partials
  gemm_kernel<1, 3><<<dim3(128, 2, 3), 256, 0, stream>>>(f1, W2T, P, nullptr, nullptr,
      1024, 9216, 3, -64, 8, 3, 1.0f, nullptr, nullptr, 0, 256, 4194304);

  final_kernel<<<4096, 256, 0, stream>>>(x2, P, b2, (float*)d_out);
}

// Round 3
// 546.025 us; speedup vs baseline: 1.3437x; 1.3437x over previous
//
#include <hip/hip_runtime.h>
#include <stdint.h>

typedef uint16_t u16;
typedef uint32_t u32;

typedef __attribute__((ext_vector_type(8))) short bf16x8;
typedef __attribute__((ext_vector_type(4))) float f32x4;

typedef __attribute__((address_space(1))) const u32 gas_u32;
typedef __attribute__((address_space(3))) u32 las_u32;

#define S_LEN 4096
#define HDIM  256
#define FFDIM 1024

__device__ __forceinline__ float bf2f(u16 u) { return __uint_as_float(((u32)u) << 16); }
__device__ __forceinline__ u16 f2bf(float f) {
  u32 x = __float_as_uint(f);
  return (u16)((x + 0x7fffu + ((x >> 16) & 1u)) >> 16);
}
__device__ __forceinline__ float gelu_f(float x) {
  return 0.5f * x * (1.0f + erff(x * 0.7071067811865475f));
}
__device__ __forceinline__ void glds16(const u16* g, u16* l) {
  __builtin_amdgcn_global_load_lds((gas_u32*)g, (las_u32*)l, 16, 0, 0);
}

// ---------------- transpose+cast (f32 [K][N] -> bf16 [N][K]) ----------------
__global__ __launch_bounds__(256) void ktranspose(const float* __restrict__ in, u16* __restrict__ out,
                                                  int K, int N) {
  __shared__ u16 t[32][33];
  const int k0 = blockIdx.x * 32, n0 = blockIdx.y * 32;
  const int tx = threadIdx.x, ty = threadIdx.y;
#pragma unroll
  for (int i = ty; i < 32; i += 8) t[i][tx] = f2bf(in[(long)(k0 + i) * N + (n0 + tx)]);
  __syncthreads();
#pragma unroll
  for (int i = ty; i < 32; i += 8) out[(long)(n0 + i) * K + (k0 + tx)] = t[tx][i];
}

// ---------------- layernorm (ddof=1, eps added to std) ----------------
template <int OUTBF>
__global__ __launch_bounds__(256) void ln_kernel(const float* __restrict__ inv, void* __restrict__ outv,
                                                 const float* __restrict__ g, const float* __restrict__ bsh) {
  const int tid = threadIdx.x;
  const int lane = tid & 63;
  const long row = (long)blockIdx.x * 4 + (tid >> 6);
  const int c0 = lane * 4;
  float v[4];
  float4 f = *(const float4*)(inv + row * HDIM + c0);
  v[0] = f.x; v[1] = f.y; v[2] = f.z; v[3] = f.w;
  float s = v[0] + v[1] + v[2] + v[3];
#pragma unroll
  for (int o = 32; o > 0; o >>= 1) s += __shfl_xor(s, o);
  const float mean = s * (1.0f / 256.0f);
  float ss = 0.f;
#pragma unroll
  for (int j = 0; j < 4; ++j) { float d = v[j] - mean; ss += d * d; }
#pragma unroll
  for (int o = 32; o > 0; o >>= 1) ss += __shfl_xor(ss, o);
  const float inv_ = 1.0f / (sqrtf(ss * (1.0f / 255.0f)) + 1e-9f);
  float y[4];
#pragma unroll
  for (int j = 0; j < 4; ++j) y[j] = g[c0 + j] * (v[j] - mean) * inv_ + bsh[c0 + j];
  if (OUTBF) {
    uint2 o_;
    o_.x = (u32)f2bf(y[0]) | ((u32)f2bf(y[1]) << 16);
    o_.y = (u32)f2bf(y[2]) | ((u32)f2bf(y[3]) << 16);
    *(uint2*)((u16*)outv + row * HDIM + c0) = o_;
  } else {
    float4 o_; o_.x = y[0]; o_.y = y[1]; o_.z = y[2]; o_.w = y[3];
    *(float4*)((float*)outv + row * HDIM + c0) = o_;
  }
}

// ------- depthwise 9-tap + gelu, then fused pw transforms -> gq,gk,gv (bf16) -------
__global__ __launch_bounds__(256) void dwconv_qkv(const float* __restrict__ xn,
                                                  u16* __restrict__ gq, u16* __restrict__ gk, u16* __restrict__ gv,
                                                  const float* __restrict__ dw_w, const float* __restrict__ dw_b,
                                                  const float* __restrict__ pw_w, const float* __restrict__ pw_b) {
  const int tid = threadIdx.x;
  const int lane = tid & 63;
  const long row = (long)blockIdx.x * 4 + (tid >> 6);
  const int sl = (int)(row & (S_LEN - 1));
  const float b0 = dw_b[0];
  float a0 = b0, a1 = b0, a2 = b0, a3 = b0;
#pragma unroll
  for (int t = 0; t < 9; ++t) {
    const int s2 = sl + t - 4;
    if (s2 >= 0 && s2 < S_LEN) {
      const float w = dw_w[t];
      float4 xv = *(const float4*)(xn + (row + t - 4) * HDIM + lane * 4);
      a0 = fmaf(w, xv.x, a0); a1 = fmaf(w, xv.y, a1);
      a2 = fmaf(w, xv.z, a2); a3 = fmaf(w, xv.w, a3);
    }
  }
  float h[4];
  h[0] = gelu_f(a0); h[1] = gelu_f(a1); h[2] = gelu_f(a2); h[3] = gelu_f(a3);
  u16* outs[3] = {gq, gk, gv};
#pragma unroll
  for (int p = 0; p < 3; ++p) {
    const float pw = pw_w[p], pb = pw_b[p];
    float y[4];
#pragma unroll
    for (int j = 0; j < 4; ++j) y[j] = gelu_f(fmaf(h[j], pw, pb));
    uint2 o_;
    o_.x = (u32)f2bf(y[0]) | ((u32)f2bf(y[1]) << 16);
    o_.y = (u32)f2bf(y[2]) | ((u32)f2bf(y[3]) << 16);
    *(uint2*)(outs[p] + row * HDIM + lane * 4) = o_;
  }
}

// ---------------- MFMA GEMM with global_load_lds staging ----------------
// A: bf16 [16384][KW] (with tap row-shifts); BT: bf16 [N][BPITCH] pre-transposed.
// EPI: 0 = bf16 store *oscale; 1 = f32 store + f32 residual; 2 = bf16 gelu(acc+bias);
//      3 = f32 partial store (split-K via blockIdx.z)
template <int EPI>
__global__ __launch_bounds__(256) void gemm_glds(
    const u16* __restrict__ A, const u16* __restrict__ BT, void* __restrict__ Outv,
    const float* __restrict__ bias, const float* __restrict__ residv,
    int KW, int BPITCH, int ntaps, int tap_off0, int tap_stride, int ubase_mult,
    float oscale, int N, long out_z_off) {
  __shared__ __align__(16) u16 As[128 * 64];
  __shared__ __align__(16) u16 Bs[128 * 64];
  const int tid = threadIdx.x;
  const int lane = tid & 63;
  const int wid = tid >> 6;
  const int wm = (wid & 1) * 64;
  const int wn = (wid >> 1) * 64;
  const int fm = lane & 15;
  const int fq = lane >> 4;
  const int t0 = blockIdx.x * 128;
  const int n0 = blockIdx.y * 128;
  const int ubase = blockIdx.z * ubase_mult;
  const bool boundary = (t0 & (S_LEN - 1)) == 0;

  // staging lane coords: row-in-8-group + XOR-swizzled 16B granule
  const int srow = lane >> 3;                    // 0..7
  const int cseg = (((lane & 7) ^ srow) << 3);   // u16 index of granule this lane fetches

  f32x4 acc[4][4];
#pragma unroll
  for (int a = 0; a < 4; ++a)
#pragma unroll
    for (int b = 0; b < 4; ++b) acc[a][b] = (f32x4){0.f, 0.f, 0.f, 0.f};

  u16* alb = &As[wid * 32 * 64];
  u16* blb = &Bs[wid * 32 * 64];

  for (int u = 0; u < ntaps; ++u) {
    const int ug = ubase + u;
    const int toff = tap_off0 + ug * tap_stride;
    const long bcolbase = (long)ug * KW;
    for (int k0 = 0; k0 < KW; k0 += 64) {
      // async stage A and B (16B/lane, swizzled granules), 32 rows per wave
      const long ar0 = ((long)(t0 + wid * 32 + srow) + toff) * KW + k0 + cseg;
      const long br0 = (long)(n0 + wid * 32 + srow) * BPITCH + bcolbase + k0 + cseg;
      const u16* ag = A + ar0;
      const u16* bg = BT + br0;
#pragma unroll
      for (int j = 0; j < 4; ++j) {
        glds16(ag + (long)(8 * j) * KW, alb + j * 8 * 64);
        glds16(bg + (long)(8 * j) * BPITCH, blb + j * 8 * 64);
      }
      __syncthreads();
      if (boundary && toff < 0) {
        // rows 0..-toff-1 precede the sequence: zero them in LDS
        const int zrows = -toff;
        for (int rz = tid >> 3; rz < zrows; rz += 32)
          *(uint4*)&As[rz * 64 + (tid & 7) * 8] = (uint4){0u, 0u, 0u, 0u};
        __syncthreads();
      }
#pragma unroll
      for (int kk = 0; kk < 2; ++kk) {
        const int g = kk * 4 + fq;
        bf16x8 af[4], bfv[4];
#pragma unroll
        for (int t = 0; t < 4; ++t) {
          const int ra = wm + t * 16 + fm;
          af[t] = *(const bf16x8*)&As[ra * 64 + ((g ^ (ra & 7)) << 3)];
          const int rb = wn + t * 16 + fm;
          bfv[t] = *(const bf16x8*)&Bs[rb * 64 + ((g ^ (rb & 7)) << 3)];
        }
#pragma unroll
        for (int mi = 0; mi < 4; ++mi)
#pragma unroll
          for (int ni = 0; ni < 4; ++ni)
            acc[mi][ni] = __builtin_amdgcn_mfma_f32_16x16x32_bf16(af[mi], bfv[ni], acc[mi][ni], 0, 0, 0);
      }
      __syncthreads();
    }
  }

  // epilogue: C/D layout col = lane&15, row = (lane>>4)*4 + reg
#pragma unroll
  for (int mi = 0; mi < 4; ++mi)
#pragma unroll
    for (int ni = 0; ni < 4; ++ni)
#pragma unroll
      for (int r = 0; r < 4; ++r) {
        const long trow = t0 + wm + mi * 16 + fq * 4 + r;
        const int col = n0 + wn + ni * 16 + fm;
        const float cv = acc[mi][ni][r];
        if (EPI == 0) {
          ((u16*)Outv)[trow * N + col] = f2bf(cv * oscale);
        } else if (EPI == 1) {
          ((float*)Outv)[trow * N + col] = cv + residv[trow * N + col];
        } else if (EPI == 2) {
          ((u16*)Outv)[trow * N + col] = f2bf(gelu_f(cv + bias[col]));
        } else {
          (((float*)Outv) + (long)blockIdx.z * out_z_off)[trow * N + col] = cv;
        }
      }
}

// ---------------- sliding-window attention (VALU online softmax) ----------------
__global__ __launch_bounds__(256) void attn_kernel(const u16* __restrict__ Q, const u16* __restrict__ K,
                                                   const u16* __restrict__ V, const float* __restrict__ rel,
                                                   u16* __restrict__ CTX) {
  __shared__ __align__(16) u16 ks[384 * 36];
  __shared__ __align__(16) u16 vs[384 * 36];
  __shared__ float bias_s[257];
  const int c = blockIdx.x, h = blockIdx.y, b = blockIdx.z;
  const int tid = threadIdx.x;
  const int i = tid & 127, phi = tid >> 7;
  const int j0 = c * 128 - 128;
  const long hb = ((long)b * S_LEN) * HDIM + h * 32;

  for (int idx = tid; idx < 384 * 4; idx += 256) {
    const int jj = idx >> 2, seg = (idx & 3) * 8;
    const int j = j0 + jj;
    uint4 ku = {0u, 0u, 0u, 0u}, vu = {0u, 0u, 0u, 0u};
    if (j >= 0 && j < S_LEN) {
      ku = *(const uint4*)(K + hb + (long)j * HDIM + seg);
      vu = *(const uint4*)(V + hb + (long)j * HDIM + seg);
    }
    uint2 a, bb;
    a.x = ku.x; a.y = ku.y; bb.x = ku.z; bb.y = ku.w;
    *(uint2*)&ks[jj * 36 + seg] = a;
    *(uint2*)&ks[jj * 36 + seg + 4] = bb;
    a.x = vu.x; a.y = vu.y; bb.x = vu.z; bb.y = vu.w;
    *(uint2*)&vs[jj * 36 + seg] = a;
    *(uint2*)&vs[jj * 36 + seg + 4] = bb;
  }
  for (int idx = tid; idx < 257; idx += 256) bias_s[idx] = rel[idx];
  __syncthreads();

  const int s = c * 128 + i;
  float qr[32];
  {
    const uint4* qp = (const uint4*)(Q + hb + (long)s * HDIM);
#pragma unroll
    for (int w = 0; w < 4; ++w) {
      uint4 u = qp[w];
      u32 uu[4] = {u.x, u.y, u.z, u.w};
#pragma unroll
      for (int e = 0; e < 4; ++e) {
        qr[w * 8 + e * 2] = __uint_as_float(uu[e] << 16);
        qr[w * 8 + e * 2 + 1] = __uint_as_float(uu[e] & 0xffff0000u);
      }
    }
  }
  const int rlo = (128 - s) > 0 ? (128 - s) : 0;
  const int rhi = (4223 - s) < 256 ? (4223 - s) : 256;
  float m = -1e30f, l = 0.f;
  float acc[32];
#pragma unroll
  for (int d = 0; d < 32; ++d) acc[d] = 0.f;

  for (int r = rlo + phi; r <= rhi; r += 2) {
    const u16* kr = &ks[(i + r) * 36];
    float d0 = 0.f, d1 = 0.f, d2 = 0.f, d3 = 0.f;
#pragma unroll
    for (int d = 0; d < 32; d += 8) {
      const u32 p0 = *(const u32*)(kr + d);
      const u32 p1 = *(const u32*)(kr + d + 2);
      const u32 p2 = *(const u32*)(kr + d + 4);
      const u32 p3 = *(const u32*)(kr + d + 6);
      d0 = fmaf(qr[d], __uint_as_float(p0 << 16), d0);
      d0 = fmaf(qr[d + 1], __uint_as_float(p0 & 0xffff0000u), d0);
      d1 = fmaf(qr[d + 2], __uint_as_float(p1 << 16), d1);
      d1 = fmaf(qr[d + 3], __uint_as_float(p1 & 0xffff0000u), d1);
      d2 = fmaf(qr[d + 4], __uint_as_float(p2 << 16), d2);
      d2 = fmaf(qr[d + 5], __uint_as_float(p2 & 0xffff0000u), d2);
      d3 = fmaf(qr[d + 6], __uint_as_float(p3 << 16), d3);
      d3 = fmaf(qr[d + 7], __uint_as_float(p3 & 0xffff0000u), d3);
    }
    const float sc_ = (d0 + d1) + (d2 + d3) + bias_s[r];
    float e;
    if (sc_ > m) {
      const float scale = __expf(m - sc_);
      l *= scale;
#pragma unroll
      for (int d = 0; d < 32; ++d) acc[d] *= scale;
      m = sc_;
      e = 1.f;
    } else {
      e = __expf(sc_ - m);
    }
    l += e;
    const u16* vr = &vs[(i + r) * 36];
#pragma unroll
    for (int d = 0; d < 32; d += 2) {
      const u32 p = *(const u32*)(vr + d);
      acc[d] = fmaf(e, __uint_as_float(p << 16), acc[d]);
      acc[d + 1] = fmaf(e, __uint_as_float(p & 0xffff0000u), acc[d + 1]);
    }
  }

  __syncthreads();
  float* scr = (float*)(void*)ks;  // overlay merge scratch on ks (done with it)
  if (phi == 1) {
    float* p = scr + i * 34;
    p[0] = m; p[1] = l;
#pragma unroll
    for (int d = 0; d < 32; ++d) p[2 + d] = acc[d];
  }
  __syncthreads();
  if (phi == 0) {
    const float* p = scr + i * 34;
    const float m1 = p[0], l1 = p[1];
    const float M = fmaxf(m, m1);
    const float a0 = __expf(m - M), a1 = __expf(m1 - M);
    const float inv = 1.0f / (l * a0 + l1 * a1);
    u32 ob[16];
#pragma unroll
    for (int d = 0; d < 32; d += 2) {
      const float o0 = (acc[d] * a0 + p[2 + d] * a1) * inv;
      const float o1 = (acc[d + 1] * a0 + p[2 + d + 1] * a1) * inv;
      ob[d >> 1] = (u32)f2bf(o0) | ((u32)f2bf(o1) << 16);
    }
    uint4* op = (uint4*)(CTX + hb + (long)s * HDIM);
    const uint4* obv = (const uint4*)ob;
    op[0] = obv[0]; op[1] = obv[1]; op[2] = obv[2]; op[3] = obv[3];
  }
}

// ---------------- final: out = x2 + gelu(P0+P1+P2 + b2)  (f32 out) ----------------
__global__ __launch_bounds__(256) void final_kernel(const float* __restrict__ x2, const float* __restrict__ P,
                                                    const float* __restrict__ b2, float* __restrict__ out) {
  const long i4 = ((long)blockIdx.x * 256 + threadIdx.x) * 4;
  const int c0 = (int)(i4 & (HDIM - 1));
  float4 xa = *(const float4*)(x2 + i4);
  float4 p0 = *(const float4*)(P + i4);
  float4 p1 = *(const float4*)(P + 4194304 + i4);
  float4 p2 = *(const float4*)(P + 8388608 + i4);
  const float pv[4] = {p0.x + p1.x + p2.x, p0.y + p1.y + p2.y, p0.z + p1.z + p2.z, p0.w + p1.w + p2.w};
  float4 o_;
  o_.x = xa.x + gelu_f(pv[0] + b2[c0 + 0]);
  o_.y = xa.y + gelu_f(pv[1] + b2[c0 + 1]);
  o_.z = xa.z + gelu_f(pv[2] + b2[c0 + 2]);
  o_.w = xa.w + gelu_f(pv[3] + b2[c0 + 3]);
  *(float4*)(out + i4) = o_;
}

extern "C" void kernel_launch(void* const* d_in, const int* in_sizes, int n_in,
                              void* d_out, int out_size, void* d_ws, size_t ws_size,
                              hipStream_t stream) {
  (void)in_sizes; (void)n_in; (void)out_size;
  const float* X    = (const float*)d_in[0];
  const float* dw_w = (const float*)d_in[1];
  const float* dw_b = (const float*)d_in[2];
  const float* pw_w = (const float*)d_in[3];
  const float* pw_b = (const float*)d_in[4];
  const float* Wq   = (const float*)d_in[5];
  const float* Wk   = (const float*)d_in[6];
  const float* Wv   = (const float*)d_in[7];
  const float* Wo   = (const float*)d_in[8];
  const float* rel  = (const float*)d_in[9];
  const float* ln1g = (const float*)d_in[10];
  const float* ln1b = (const float*)d_in[11];
  const float* ln2g = (const float*)d_in[12];
  const float* ln2b = (const float*)d_in[13];
  const float* w1   = (const float*)d_in[14];
  const float* b1   = (const float*)d_in[15];
  const float* w2   = (const float*)d_in[16];
  const float* b2   = (const float*)d_in[17];

  if (ws_size < 119537664) return;  // need exactly 114 MiB

  char* ws = (char*)d_ws;
  u16* WqT = (u16*)(ws + 0);
  u16* WkT = (u16*)(ws + 131072);
  u16* WvT = (u16*)(ws + 262144);
  u16* WoT = (u16*)(ws + 393216);
  u16* W1T = (u16*)(ws + 524288);
  u16* W2T = (u16*)(ws + 524288 + 4718592);
  const size_t R1 = 10485760;  // 10 MiB weights region
  const size_t MB = 1048576;
  float* xn  = (float*)(ws + R1);            // 16 MiB, reused as x2
  float* x2  = xn;
  u16* gq  = (u16*)(ws + R1 + 16 * MB);      // 8 MiB  } dead after attn;
  u16* gk  = (u16*)(ws + R1 + 24 * MB);      // 8 MiB  } P (48 MiB fp32 partials)
  u16* gv  = (u16*)(ws + R1 + 32 * MB);      // 8 MiB  } overlays gq..v/q..v
  u16* q   = (u16*)(ws + R1 + 40 * MB);      // 8 MiB
  u16* k   = (u16*)(ws + R1 + 48 * MB);      // 8 MiB
  u16* v   = (u16*)(ws + R1 + 56 * MB);      // 8 MiB
  float* P = (float*)(ws + R1 + 16 * MB);    // overlay
  u16* ctx = (u16*)(ws + R1 + 64 * MB);      // 8 MiB, dead after Wo gemm
  u16* xn2 = (u16*)(ws + R1 + 64 * MB);      // overlays ctx
  u16* f1  = (u16*)(ws + R1 + 72 * MB);      // 32 MiB

  dim3 tb(32, 8);
  ktranspose<<<dim3(8, 8), tb, 0, stream>>>(Wq, WqT, 256, 256);
  ktranspose<<<dim3(8, 8), tb, 0, stream>>>(Wk, WkT, 256, 256);
  ktranspose<<<dim3(8, 8), tb, 0, stream>>>(Wv, WvT, 256, 256);
  ktranspose<<<dim3(8, 8), tb, 0, stream>>>(Wo, WoT, 256, 256);
  ktranspose<<<dim3(72, 32), tb, 0, stream>>>(w1, W1T, 2304, 1024);
  ktranspose<<<dim3(288, 8), tb, 0, stream>>>(w2, W2T, 9216, 256);

  ln_kernel<0><<<4096, 256, 0, stream>>>(X, xn, ln1g, ln1b);
  dwconv_qkv<<<4096, 256, 0, stream>>>(xn, gq, gk, gv, dw_w, dw_b, pw_w, pw_b);

  const float qscale = 0.17677669529663687f;  // DH^-0.5
  gemm_glds<0><<<dim3(128, 2), 256, 0, stream>>>(gq, WqT, q, nullptr, nullptr,
      256, 256, 1, 0, 0, 0, qscale, 256, 0);
  gemm_glds<0><<<dim3(128, 2), 256, 0, stream>>>(gk, WkT, k, nullptr, nullptr,
      256, 256, 1, 0, 0, 0, 1.0f, 256, 0);
  gemm_glds<0><<<dim3(128, 2), 256, 0, stream>>>(gv, WvT, v, nullptr, nullptr,
      256, 256, 1, 0, 0, 0, 1.0f, 256, 0);

  attn_kernel<<<dim3(32, 8, 4), 256, 0, stream>>>(q, k, v, rel, ctx);

  gemm_glds<1><<<dim3(128, 2), 256, 0, stream>>>(ctx, WoT, x2, nullptr, X,
      256, 256, 1, 0, 0, 0, 1.0f, 256, 0);

  ln_kernel<1><<<4096, 256, 0, stream>>>(x2, xn2, ln2g, ln2b);

  // conv1: K = 9 taps x 256, shifts u-8 (causal), N=1024, gelu+bias epilogue -> f1 (bf16)
  gemm_glds<2><<<dim3(128, 8), 256, 0, stream>>>(xn2, W1T, f1, b1, nullptr,
      256, 2304, 9, -8, 1, 0, 1.0f, 1024, 0);

  // conv2: K = 9 taps x 1024, shifts 8u-64, split-K x3 over grid.z -> fp32 partials
  gemm_glds<3><<<dim3(128, 2, 3), 256, 0, stream>>>(f1, W2T, P, nullptr, nullptr,
      1024, 9216, 3, -64, 8, 3, 1.0f, 256, 4194304);

  final_kernel<<<4096, 256, 0, stream>>>(x2, P, b2, (float*)d_out);
}

// Round 5
// 519.936 us; speedup vs baseline: 1.4111x; 1.0502x over previous
//
#include <hip/hip_runtime.h>
#include <stdint.h>

typedef uint16_t u16;
typedef uint32_t u32;

typedef __attribute__((ext_vector_type(8))) short bf16x8;
typedef __attribute__((ext_vector_type(4))) float f32x4;

typedef __attribute__((address_space(1))) const u32 gas_u32;
typedef __attribute__((address_space(3))) u32 las_u32;

#define S_LEN 4096
#define HDIM  256
#define FFDIM 1024

__device__ __forceinline__ float bf2f(u16 u) { return __uint_as_float(((u32)u) << 16); }
__device__ __forceinline__ u16 f2bf(float f) {
  u32 x = __float_as_uint(f);
  return (u16)((x + 0x7fffu + ((x >> 16) & 1u)) >> 16);
}
__device__ __forceinline__ float gelu_f(float x) {
  return 0.5f * x * (1.0f + erff(x * 0.7071067811865475f));
}
__device__ __forceinline__ void glds16(const u16* g, u16* l) {
  __builtin_amdgcn_global_load_lds((gas_u32*)g, (las_u32*)l, 16, 0, 0);
}

// ---------------- zero guard rows of padded buffers ----------------
// MUST run after all overlapping phase-1 buffers (gq..v,q,k,v,ctx) are dead.
__global__ __launch_bounds__(256) void zero_guards(uint4* __restrict__ xn2p, uint4* __restrict__ f1p) {
  int t = blockIdx.x * 256 + threadIdx.x;
  const uint4 z = {0u, 0u, 0u, 0u};
  if (t < 1024) {
    const int s = t >> 8, o = t & 255;
    xn2p[(long)s * 131328 + o] = z;        // 4104*256*2/16 = 131328
  } else {
    t -= 1024;
    if (t < 32768) {
      const int s = t >> 13, o = t & 8191;
      f1p[(long)s * 532480 + o] = z;       // 4160*1024*2/16 = 532480
    }
  }
}

// ---------------- transpose+cast+scale (f32 [K][N] -> bf16 [N][K]) ----------------
__global__ __launch_bounds__(256) void ktranspose(const float* __restrict__ in, u16* __restrict__ out,
                                                  int K, int N, float scale) {
  __shared__ u16 t[32][33];
  const int k0 = blockIdx.x * 32, n0 = blockIdx.y * 32;
  const int tx = threadIdx.x, ty = threadIdx.y;
#pragma unroll
  for (int i = ty; i < 32; i += 8) t[i][tx] = f2bf(in[(long)(k0 + i) * N + (n0 + tx)] * scale);
  __syncthreads();
#pragma unroll
  for (int i = ty; i < 32; i += 8) out[(long)(n0 + i) * K + (k0 + tx)] = t[tx][i];
}

// ---------------- layernorm (ddof=1, eps added to std) ----------------
template <int OUTBF>
__global__ __launch_bounds__(256) void ln_kernel(const float* __restrict__ inv, void* __restrict__ outv,
                                                 const float* __restrict__ g, const float* __restrict__ bsh,
                                                 int OSEGR, int OGUARD) {
  const int tid = threadIdx.x;
  const int lane = tid & 63;
  const long row = (long)blockIdx.x * 4 + (tid >> 6);
  const int c0 = lane * 4;
  float v[4];
  float4 f = *(const float4*)(inv + row * HDIM + c0);
  v[0] = f.x; v[1] = f.y; v[2] = f.z; v[3] = f.w;
  float s = v[0] + v[1] + v[2] + v[3];
#pragma unroll
  for (int o = 32; o > 0; o >>= 1) s += __shfl_xor(s, o);
  const float mean = s * (1.0f / 256.0f);
  float ss = 0.f;
#pragma unroll
  for (int j = 0; j < 4; ++j) { float d = v[j] - mean; ss += d * d; }
#pragma unroll
  for (int o = 32; o > 0; o >>= 1) ss += __shfl_xor(ss, o);
  const float inv_ = 1.0f / (sqrtf(ss * (1.0f / 255.0f)) + 1e-9f);
  float y[4];
#pragma unroll
  for (int j = 0; j < 4; ++j) y[j] = g[c0 + j] * (v[j] - mean) * inv_ + bsh[c0 + j];
  if (OUTBF) {
    const long orow = (row >> 12) * OSEGR + OGUARD + (row & (S_LEN - 1));
    uint2 o_;
    o_.x = (u32)f2bf(y[0]) | ((u32)f2bf(y[1]) << 16);
    o_.y = (u32)f2bf(y[2]) | ((u32)f2bf(y[3]) << 16);
    *(uint2*)((u16*)outv + orow * HDIM + c0) = o_;
  } else {
    float4 o_; o_.x = y[0]; o_.y = y[1]; o_.z = y[2]; o_.w = y[3];
    *(float4*)((float*)outv + row * HDIM + c0) = o_;
  }
}

// ------- depthwise 9-tap + gelu, then fused pw transforms -> gq,gk,gv (bf16) -------
__global__ __launch_bounds__(256) void dwconv_qkv(const float* __restrict__ xn,
                                                  u16* __restrict__ gq, u16* __restrict__ gk, u16* __restrict__ gv,
                                                  const float* __restrict__ dw_w, const float* __restrict__ dw_b,
                                                  const float* __restrict__ pw_w, const float* __restrict__ pw_b) {
  const int tid = threadIdx.x;
  const int lane = tid & 63;
  const long row = (long)blockIdx.x * 4 + (tid >> 6);
  const int sl = (int)(row & (S_LEN - 1));
  const float b0 = dw_b[0];
  float a0 = b0, a1 = b0, a2 = b0, a3 = b0;
#pragma unroll
  for (int t = 0; t < 9; ++t) {
    const int s2 = sl + t - 4;
    if (s2 >= 0 && s2 < S_LEN) {
      const float w = dw_w[t];
      float4 xv = *(const float4*)(xn + (row + t - 4) * HDIM + lane * 4);
      a0 = fmaf(w, xv.x, a0); a1 = fmaf(w, xv.y, a1);
      a2 = fmaf(w, xv.z, a2); a3 = fmaf(w, xv.w, a3);
    }
  }
  float h[4];
  h[0] = gelu_f(a0); h[1] = gelu_f(a1); h[2] = gelu_f(a2); h[3] = gelu_f(a3);
  u16* outs[3] = {gq, gk, gv};
#pragma unroll
  for (int p = 0; p < 3; ++p) {
    const float pw = pw_w[p], pb = pw_b[p];
    float y[4];
#pragma unroll
    for (int j = 0; j < 4; ++j) y[j] = gelu_f(fmaf(h[j], pw, pb));
    uint2 o_;
    o_.x = (u32)f2bf(y[0]) | ((u32)f2bf(y[1]) << 16);
    o_.y = (u32)f2bf(y[2]) | ((u32)f2bf(y[3]) << 16);
    *(uint2*)(outs[p] + row * HDIM + lane * 4) = o_;
  }
}

// ---------------- plain MFMA GEMM (QKV via grid.z offsets / Wo+residual) ----------------
template <int EPI>
__global__ __launch_bounds__(256) void gemm_glds(
    const u16* __restrict__ A, const u16* __restrict__ BT, void* __restrict__ Outv,
    const float* __restrict__ residv, int KW, int N,
    long a_z, long b_z, long o_z) {
  __shared__ __align__(16) u16 As[128 * 64];
  __shared__ __align__(16) u16 Bs[128 * 64];
  const int tid = threadIdx.x;
  const int lane = tid & 63;
  const int wid = tid >> 6;
  const int wm = (wid & 1) * 64;
  const int wn = (wid >> 1) * 64;
  const int fm = lane & 15;
  const int fq = lane >> 4;
  const int t0 = blockIdx.x * 128;
  const int n0 = blockIdx.y * 128;
  A += (long)blockIdx.z * a_z;
  BT += (long)blockIdx.z * b_z;

  const int srow = lane >> 3;
  const int cseg = (((lane & 7) ^ srow) << 3);

  f32x4 acc[4][4];
#pragma unroll
  for (int a = 0; a < 4; ++a)
#pragma unroll
    for (int b = 0; b < 4; ++b) acc[a][b] = (f32x4){0.f, 0.f, 0.f, 0.f};

  u16* alb = &As[wid * 32 * 64];
  u16* blb = &Bs[wid * 32 * 64];

  for (int k0 = 0; k0 < KW; k0 += 64) {
    const u16* ag = A + (long)(t0 + wid * 32 + srow) * KW + k0 + cseg;
    const u16* bg = BT + (long)(n0 + wid * 32 + srow) * KW + k0 + cseg;
#pragma unroll
    for (int j = 0; j < 4; ++j) {
      glds16(ag + (long)(8 * j) * KW, alb + j * 8 * 64);
      glds16(bg + (long)(8 * j) * KW, blb + j * 8 * 64);
    }
    __syncthreads();
#pragma unroll
    for (int kk = 0; kk < 2; ++kk) {
      const int g = kk * 4 + fq;
      bf16x8 af[4], bfv[4];
#pragma unroll
      for (int t = 0; t < 4; ++t) {
        const int ra = wm + t * 16 + fm;
        af[t] = *(const bf16x8*)&As[ra * 64 + ((g ^ (ra & 7)) << 3)];
        const int rb = wn + t * 16 + fm;
        bfv[t] = *(const bf16x8*)&Bs[rb * 64 + ((g ^ (rb & 7)) << 3)];
      }
#pragma unroll
      for (int mi = 0; mi < 4; ++mi)
#pragma unroll
        for (int ni = 0; ni < 4; ++ni)
          acc[mi][ni] = __builtin_amdgcn_mfma_f32_16x16x32_bf16(af[mi], bfv[ni], acc[mi][ni], 0, 0, 0);
    }
    __syncthreads();
  }

#pragma unroll
  for (int mi = 0; mi < 4; ++mi)
#pragma unroll
    for (int ni = 0; ni < 4; ++ni)
#pragma unroll
      for (int r = 0; r < 4; ++r) {
        const long trow = t0 + wm + mi * 16 + fq * 4 + r;
        const int col = n0 + wn + ni * 16 + fm;
        const float cv = acc[mi][ni][r];
        if (EPI == 0) {
          ((u16*)Outv + (long)blockIdx.z * o_z)[trow * N + col] = f2bf(cv);
        } else {
          ((float*)Outv)[trow * N + col] = cv + residv[trow * N + col];
        }
      }
}

// ---------------- conv MFMA GEMM: tap-shared A tile + double-buffered B ----------------
template <int EPI>
__global__ __launch_bounds__(256) void gemm_conv(
    const u16* __restrict__ Apad, const u16* __restrict__ BT, void* __restrict__ Outv,
    const float* __restrict__ bias,
    int APITCH, int SEGR, int BPITCH, int ntaps, int dil,
    int N, int OSEGR, int OGUARD, long out_z_off) {
  __shared__ __align__(16) u16 As[144 * 64];
  __shared__ __align__(16) u16 Bs2[2][128 * 64];
  const int tid = threadIdx.x;
  const int lane = tid & 63;
  const int wid = tid >> 6;
  const int wm = (wid & 1) * 64;
  const int wn = (wid >> 1) * 64;
  const int fm = lane & 15;
  const int fq = lane >> 4;
  const int t0 = blockIdx.x * 128;
  const int n0 = blockIdx.y * 128;
  const int tap0 = blockIdx.z * ntaps;

  const int seg = t0 >> 12;
  const long abase = (long)seg * SEGR + (t0 & (S_LEN - 1)) + (long)tap0 * dil;
  const int aops = (128 + (ntaps - 1) * dil + 7) >> 3;

  const int srow = lane >> 3;
  const int cseg = (((lane & 7) ^ srow) << 3);

  f32x4 acc[4][4];
#pragma unroll
  for (int a = 0; a < 4; ++a)
#pragma unroll
    for (int b = 0; b < 4; ++b) acc[a][b] = (f32x4){0.f, 0.f, 0.f, 0.f};

  for (int k0 = 0; k0 < APITCH; k0 += 64) {
    for (int op = wid; op < aops; op += 4)
      glds16(Apad + (abase + op * 8 + srow) * APITCH + k0 + cseg, &As[op * 8 * 64]);
    {
      const long bc = (long)tap0 * APITCH + k0;
#pragma unroll
      for (int j = 0; j < 4; ++j)
        glds16(BT + (long)(n0 + wid * 32 + j * 8 + srow) * BPITCH + bc + cseg,
               &Bs2[0][(wid * 32 + j * 8) * 64]);
    }
    __syncthreads();
    for (int u = 0; u < ntaps; ++u) {
      if (u + 1 < ntaps) {
        const long bc = (long)(tap0 + u + 1) * APITCH + k0;
#pragma unroll
        for (int j = 0; j < 4; ++j)
          glds16(BT + (long)(n0 + wid * 32 + j * 8 + srow) * BPITCH + bc + cseg,
                 &Bs2[(u + 1) & 1][(wid * 32 + j * 8) * 64]);
      }
      const int du = u * dil;
      const u16* bsp = Bs2[u & 1];
#pragma unroll
      for (int kk = 0; kk < 2; ++kk) {
        const int g = kk * 4 + fq;
        bf16x8 af[4], bfv[4];
#pragma unroll
        for (int t = 0; t < 4; ++t) {
          const int ra = wm + t * 16 + fm + du;
          af[t] = *(const bf16x8*)&As[ra * 64 + ((g ^ (ra & 7)) << 3)];
          const int rb = wn + t * 16 + fm;
          bfv[t] = *(const bf16x8*)&bsp[rb * 64 + ((g ^ (rb & 7)) << 3)];
        }
#pragma unroll
        for (int mi = 0; mi < 4; ++mi)
#pragma unroll
          for (int ni = 0; ni < 4; ++ni)
            acc[mi][ni] = __builtin_amdgcn_mfma_f32_16x16x32_bf16(af[mi], bfv[ni], acc[mi][ni], 0, 0, 0);
      }
      __syncthreads();
    }
  }

#pragma unroll
  for (int mi = 0; mi < 4; ++mi)
#pragma unroll
    for (int ni = 0; ni < 4; ++ni)
#pragma unroll
      for (int r = 0; r < 4; ++r) {
        const long trow = t0 + wm + mi * 16 + fq * 4 + r;
        const int col = n0 + wn + ni * 16 + fm;
        const float cv = acc[mi][ni][r];
        if (EPI == 2) {
          const long orow = (trow >> 12) * OSEGR + OGUARD + (trow & (S_LEN - 1));
          ((u16*)Outv)[orow * N + col] = f2bf(gelu_f(cv + bias[col]));
        } else {
          (((float*)Outv) + (long)blockIdx.z * out_z_off)[trow * N + col] = cv;
        }
      }
}

// ---------------- sliding-window attention (VALU online softmax) ----------------
__global__ __launch_bounds__(256) void attn_kernel(const u16* __restrict__ Q, const u16* __restrict__ K,
                                                   const u16* __restrict__ V, const float* __restrict__ rel,
                                                   u16* __restrict__ CTX) {
  __shared__ __align__(16) u16 ks[384 * 36];
  __shared__ __align__(16) u16 vs[384 * 36];
  __shared__ float bias_s[257];
  const int c = blockIdx.x, h = blockIdx.y, b = blockIdx.z;
  const int tid = threadIdx.x;
  const int i = tid & 127, phi = tid >> 7;
  const int j0 = c * 128 - 128;
  const long hb = ((long)b * S_LEN) * HDIM + h * 32;

  for (int idx = tid; idx < 384 * 4; idx += 256) {
    const int jj = idx >> 2, seg = (idx & 3) * 8;
    const int j = j0 + jj;
    uint4 ku = {0u, 0u, 0u, 0u}, vu = {0u, 0u, 0u, 0u};
    if (j >= 0 && j < S_LEN) {
      ku = *(const uint4*)(K + hb + (long)j * HDIM + seg);
      vu = *(const uint4*)(V + hb + (long)j * HDIM + seg);
    }
    uint2 a, bb;
    a.x = ku.x; a.y = ku.y; bb.x = ku.z; bb.y = ku.w;
    *(uint2*)&ks[jj * 36 + seg] = a;
    *(uint2*)&ks[jj * 36 + seg + 4] = bb;
    a.x = vu.x; a.y = vu.y; bb.x = vu.z; bb.y = vu.w;
    *(uint2*)&vs[jj * 36 + seg] = a;
    *(uint2*)&vs[jj * 36 + seg + 4] = bb;
  }
  for (int idx = tid; idx < 257; idx += 256) bias_s[idx] = rel[idx];
  __syncthreads();

  const int s = c * 128 + i;
  float qr[32];
  {
    const uint4* qp = (const uint4*)(Q + hb + (long)s * HDIM);
#pragma unroll
    for (int w = 0; w < 4; ++w) {
      uint4 u = qp[w];
      u32 uu[4] = {u.x, u.y, u.z, u.w};
#pragma unroll
      for (int e = 0; e < 4; ++e) {
        qr[w * 8 + e * 2] = __uint_as_float(uu[e] << 16);
        qr[w * 8 + e * 2 + 1] = __uint_as_float(uu[e] & 0xffff0000u);
      }
    }
  }
  const int rlo = (128 - s) > 0 ? (128 - s) : 0;
  const int rhi = (4223 - s) < 256 ? (4223 - s) : 256;
  float m = -1e30f, l = 0.f;
  float acc[32];
#pragma unroll
  for (int d = 0; d < 32; ++d) acc[d] = 0.f;

  for (int r = rlo + phi; r <= rhi; r += 2) {
    const u16* kr = &ks[(i + r) * 36];
    float d0 = 0.f, d1 = 0.f, d2 = 0.f, d3 = 0.f;
#pragma unroll
    for (int d = 0; d < 32; d += 8) {
      const u32 p0 = *(const u32*)(kr + d);
      const u32 p1 = *(const u32*)(kr + d + 2);
      const u32 p2 = *(const u32*)(kr + d + 4);
      const u32 p3 = *(const u32*)(kr + d + 6);
      d0 = fmaf(qr[d], __uint_as_float(p0 << 16), d0);
      d0 = fmaf(qr[d + 1], __uint_as_float(p0 & 0xffff0000u), d0);
      d1 = fmaf(qr[d + 2], __uint_as_float(p1 << 16), d1);
      d1 = fmaf(qr[d + 3], __uint_as_float(p1 & 0xffff0000u), d1);
      d2 = fmaf(qr[d + 4], __uint_as_float(p2 << 16), d2);
      d2 = fmaf(qr[d + 5], __uint_as_float(p2 & 0xffff0000u), d2);
      d3 = fmaf(qr[d + 6], __uint_as_float(p3 << 16), d3);
      d3 = fmaf(qr[d + 7], __uint_as_float(p3 & 0xffff0000u), d3);
    }
    const float sc_ = (d0 + d1) + (d2 + d3) + bias_s[r];
    float e;
    if (sc_ > m) {
      const float scale = __expf(m - sc_);
      l *= scale;
#pragma unroll
      for (int d = 0; d < 32; ++d) acc[d] *= scale;
      m = sc_;
      e = 1.f;
    } else {
      e = __expf(sc_ - m);
    }
    l += e;
    const u16* vr = &vs[(i + r) * 36];
#pragma unroll
    for (int d = 0; d < 32; d += 2) {
      const u32 p = *(const u32*)(vr + d);
      acc[d] = fmaf(e, __uint_as_float(p << 16), acc[d]);
      acc[d + 1] = fmaf(e, __uint_as_float(p & 0xffff0000u), acc[d + 1]);
    }
  }

  __syncthreads();
  float* scr = (float*)(void*)ks;
  if (phi == 1) {
    float* p = scr + i * 34;
    p[0] = m; p[1] = l;
#pragma unroll
    for (int d = 0; d < 32; ++d) p[2 + d] = acc[d];
  }
  __syncthreads();
  if (phi == 0) {
    const float* p = scr + i * 34;
    const float m1 = p[0], l1 = p[1];
    const float M = fmaxf(m, m1);
    const float a0 = __expf(m - M), a1 = __expf(m1 - M);
    const float inv = 1.0f / (l * a0 + l1 * a1);
    u32 ob[16];
#pragma unroll
    for (int d = 0; d < 32; d += 2) {
      const float o0 = (acc[d] * a0 + p[2 + d] * a1) * inv;
      const float o1 = (acc[d + 1] * a0 + p[2 + d + 1] * a1) * inv;
      ob[d >> 1] = (u32)f2bf(o0) | ((u32)f2bf(o1) << 16);
    }
    uint4* op = (uint4*)(CTX + hb + (long)s * HDIM);
    const uint4* obv = (const uint4*)ob;
    op[0] = obv[0]; op[1] = obv[1]; op[2] = obv[2]; op[3] = obv[3];
  }
}

// ---------------- final: out = x2 + gelu(P0+P1+P2 + b2)  (f32 out) ----------------
__global__ __launch_bounds__(256) void final_kernel(const float* __restrict__ x2, const float* __restrict__ P,
                                                    const float* __restrict__ b2, float* __restrict__ out) {
  const long i4 = ((long)blockIdx.x * 256 + threadIdx.x) * 4;
  const int c0 = (int)(i4 & (HDIM - 1));
  float4 xa = *(const float4*)(x2 + i4);
  float4 p0 = *(const float4*)(P + i4);
  float4 p1 = *(const float4*)(P + 4194304 + i4);
  float4 p2 = *(const float4*)(P + 8388608 + i4);
  const float pv[4] = {p0.x + p1.x + p2.x, p0.y + p1.y + p2.y, p0.z + p1.z + p2.z, p0.w + p1.w + p2.w};
  float4 o_;
  o_.x = xa.x + gelu_f(pv[0] + b2[c0 + 0]);
  o_.y = xa.y + gelu_f(pv[1] + b2[c0 + 1]);
  o_.z = xa.z + gelu_f(pv[2] + b2[c0 + 2]);
  o_.w = xa.w + gelu_f(pv[3] + b2[c0 + 3]);
  *(float4*)(out + i4) = o_;
}

extern "C" void kernel_launch(void* const* d_in, const int* in_sizes, int n_in,
                              void* d_out, int out_size, void* d_ws, size_t ws_size,
                              hipStream_t stream) {
  (void)in_sizes; (void)n_in; (void)out_size;
  const float* X    = (const float*)d_in[0];
  const float* dw_w = (const float*)d_in[1];
  const float* dw_b = (const float*)d_in[2];
  const float* pw_w = (const float*)d_in[3];
  const float* pw_b = (const float*)d_in[4];
  const float* Wq   = (const float*)d_in[5];
  const float* Wk   = (const float*)d_in[6];
  const float* Wv   = (const float*)d_in[7];
  const float* Wo   = (const float*)d_in[8];
  const float* rel  = (const float*)d_in[9];
  const float* ln1g = (const float*)d_in[10];
  const float* ln1b = (const float*)d_in[11];
  const float* ln2g = (const float*)d_in[12];
  const float* ln2b = (const float*)d_in[13];
  const float* w1   = (const float*)d_in[14];
  const float* b1   = (const float*)d_in[15];
  const float* w2   = (const float*)d_in[16];
  const float* b2   = (const float*)d_in[17];

  if (ws_size < 119537664) return;

  char* ws = (char*)d_ws;
  u16* WqT = (u16*)(ws + 0);
  u16* WkT = (u16*)(ws + 131072);
  u16* WvT = (u16*)(ws + 262144);
  u16* WoT = (u16*)(ws + 393216);
  u16* W1T = (u16*)(ws + 524288);
  u16* W2T = (u16*)(ws + 5242880);
  float* xn  = (float*)(ws + 10485760);   // 16 MiB, reused as x2
  float* x2  = xn;
  u16* gq  = (u16*)(ws + 27262976);
  u16* gk  = (u16*)(ws + 35651584);
  u16* gv  = (u16*)(ws + 44040192);
  u16* q   = (u16*)(ws + 52428800);
  u16* k   = (u16*)(ws + 60817408);
  u16* v   = (u16*)(ws + 69206016);
  u16* ctx = (u16*)(ws + 77594624);
  // phase-2 overlays (valid only after attn + Wo done)
  u16* f1p  = (u16*)(ws + 27262976);      // padded [4][4160][1024] bf16
  u16* xn2p = (u16*)(ws + 61341696);      // padded [4][4104][256] bf16
  float* P  = (float*)(ws + 61341696);    // 3 x 16 MiB fp32 partials (after conv1)

  const float qscale = 0.17677669529663687f;
  dim3 tb(32, 8);
  ktranspose<<<dim3(8, 8), tb, 0, stream>>>(Wq, WqT, 256, 256, qscale);
  ktranspose<<<dim3(8, 8), tb, 0, stream>>>(Wk, WkT, 256, 256, 1.0f);
  ktranspose<<<dim3(8, 8), tb, 0, stream>>>(Wv, WvT, 256, 256, 1.0f);
  ktranspose<<<dim3(8, 8), tb, 0, stream>>>(Wo, WoT, 256, 256, 1.0f);
  ktranspose<<<dim3(72, 32), tb, 0, stream>>>(w1, W1T, 2304, 1024, 1.0f);
  ktranspose<<<dim3(288, 8), tb, 0, stream>>>(w2, W2T, 9216, 256, 1.0f);

  ln_kernel<0><<<4096, 256, 0, stream>>>(X, xn, ln1g, ln1b, 4096, 0);
  dwconv_qkv<<<4096, 256, 0, stream>>>(xn, gq, gk, gv, dw_w, dw_b, pw_w, pw_b);

  gemm_glds<0><<<dim3(128, 2, 3), 256, 0, stream>>>(gq, WqT, q, nullptr,
      256, 256, 4194304, 65536, 4194304);

  attn_kernel<<<dim3(32, 8, 4), 256, 0, stream>>>(q, k, v, rel, ctx);

  gemm_glds<1><<<dim3(128, 2), 256, 0, stream>>>(ctx, WoT, x2, X, 256, 256, 0, 0, 0);

  // guards zeroed HERE: every buffer overlapping xn2p/f1p (gq..v,q,k,v,ctx) is now dead
  zero_guards<<<132, 256, 0, stream>>>((uint4*)xn2p, (uint4*)f1p);

  ln_kernel<1><<<4096, 256, 0, stream>>>(x2, xn2p, ln2g, ln2b, 4104, 8);

  gemm_conv<2><<<dim3(128, 8), 256, 0, stream>>>(xn2p, W1T, f1p, b1,
      256, 4104, 2304, 9, 1, 1024, 4160, 64, 0);

  gemm_conv<3><<<dim3(128, 2, 3), 256, 0, stream>>>(f1p, W2T, P, nullptr,
      1024, 4160, 9216, 3, 8, 256, 0, 0, 4194304);

  final_kernel<<<4096, 256, 0, stream>>>(x2, P, b2, (float*)d_out);
}

// Round 6
// 393.764 us; speedup vs baseline: 1.8632x; 1.3204x over previous
//
#include <hip/hip_runtime.h>
#include <stdint.h>

typedef uint16_t u16;
typedef uint32_t u32;

typedef __attribute__((ext_vector_type(8))) short bf16x8;
typedef __attribute__((ext_vector_type(4))) float f32x4;

typedef __attribute__((address_space(1))) const u32 gas_u32;
typedef __attribute__((address_space(3))) u32 las_u32;

#define S_LEN 4096
#define HDIM  256
#define FFDIM 1024

__device__ __forceinline__ float bf2f(u16 u) { return __uint_as_float(((u32)u) << 16); }
__device__ __forceinline__ u16 f2bf(float f) {
  u32 x = __float_as_uint(f);
  return (u16)((x + 0x7fffu + ((x >> 16) & 1u)) >> 16);
}
__device__ __forceinline__ float gelu_f(float x) {
  return 0.5f * x * (1.0f + erff(x * 0.7071067811865475f));
}
__device__ __forceinline__ void glds16(const u16* g, u16* l) {
  __builtin_amdgcn_global_load_lds((gas_u32*)g, (las_u32*)l, 16, 0, 0);
}

// ---------------- zero guard rows of padded buffers ----------------
__global__ __launch_bounds__(256) void zero_guards(uint4* __restrict__ xn2p, uint4* __restrict__ f1p) {
  int t = blockIdx.x * 256 + threadIdx.x;
  const uint4 z = {0u, 0u, 0u, 0u};
  if (t < 1024) {
    const int s = t >> 8, o = t & 255;
    xn2p[(long)s * 131328 + o] = z;
  } else {
    t -= 1024;
    if (t < 32768) {
      const int s = t >> 13, o = t & 8191;
      f1p[(long)s * 532480 + o] = z;
    }
  }
}

// ---------------- transpose+cast+scale (f32 [K][N] -> bf16 [N][K]) ----------------
__global__ __launch_bounds__(256) void ktranspose(const float* __restrict__ in, u16* __restrict__ out,
                                                  int K, int N, float scale) {
  __shared__ u16 t[32][33];
  const int k0 = blockIdx.x * 32, n0 = blockIdx.y * 32;
  const int tx = threadIdx.x, ty = threadIdx.y;
#pragma unroll
  for (int i = ty; i < 32; i += 8) t[i][tx] = f2bf(in[(long)(k0 + i) * N + (n0 + tx)] * scale);
  __syncthreads();
#pragma unroll
  for (int i = ty; i < 32; i += 8) out[(long)(n0 + i) * K + (k0 + tx)] = t[tx][i];
}

// ---------------- layernorm (ddof=1, eps added to std) ----------------
template <int OUTBF>
__global__ __launch_bounds__(256) void ln_kernel(const float* __restrict__ inv, void* __restrict__ outv,
                                                 const float* __restrict__ g, const float* __restrict__ bsh,
                                                 int OSEGR, int OGUARD) {
  const int tid = threadIdx.x;
  const int lane = tid & 63;
  const long row = (long)blockIdx.x * 4 + (tid >> 6);
  const int c0 = lane * 4;
  float v[4];
  float4 f = *(const float4*)(inv + row * HDIM + c0);
  v[0] = f.x; v[1] = f.y; v[2] = f.z; v[3] = f.w;
  float s = v[0] + v[1] + v[2] + v[3];
#pragma unroll
  for (int o = 32; o > 0; o >>= 1) s += __shfl_xor(s, o);
  const float mean = s * (1.0f / 256.0f);
  float ss = 0.f;
#pragma unroll
  for (int j = 0; j < 4; ++j) { float d = v[j] - mean; ss += d * d; }
#pragma unroll
  for (int o = 32; o > 0; o >>= 1) ss += __shfl_xor(ss, o);
  const float inv_ = 1.0f / (sqrtf(ss * (1.0f / 255.0f)) + 1e-9f);
  float y[4];
#pragma unroll
  for (int j = 0; j < 4; ++j) y[j] = g[c0 + j] * (v[j] - mean) * inv_ + bsh[c0 + j];
  if (OUTBF) {
    const long orow = (row >> 12) * OSEGR + OGUARD + (row & (S_LEN - 1));
    uint2 o_;
    o_.x = (u32)f2bf(y[0]) | ((u32)f2bf(y[1]) << 16);
    o_.y = (u32)f2bf(y[2]) | ((u32)f2bf(y[3]) << 16);
    *(uint2*)((u16*)outv + orow * HDIM + c0) = o_;
  } else {
    float4 o_; o_.x = y[0]; o_.y = y[1]; o_.z = y[2]; o_.w = y[3];
    *(float4*)((float*)outv + row * HDIM + c0) = o_;
  }
}

// ------- depthwise 9-tap + gelu, then fused pw transforms -> gq,gk,gv (bf16) -------
__global__ __launch_bounds__(256) void dwconv_qkv(const float* __restrict__ xn,
                                                  u16* __restrict__ gq, u16* __restrict__ gk, u16* __restrict__ gv,
                                                  const float* __restrict__ dw_w, const float* __restrict__ dw_b,
                                                  const float* __restrict__ pw_w, const float* __restrict__ pw_b) {
  const int tid = threadIdx.x;
  const int lane = tid & 63;
  const long row = (long)blockIdx.x * 4 + (tid >> 6);
  const int sl = (int)(row & (S_LEN - 1));
  const float b0 = dw_b[0];
  float a0 = b0, a1 = b0, a2 = b0, a3 = b0;
#pragma unroll
  for (int t = 0; t < 9; ++t) {
    const int s2 = sl + t - 4;
    if (s2 >= 0 && s2 < S_LEN) {
      const float w = dw_w[t];
      float4 xv = *(const float4*)(xn + (row + t - 4) * HDIM + lane * 4);
      a0 = fmaf(w, xv.x, a0); a1 = fmaf(w, xv.y, a1);
      a2 = fmaf(w, xv.z, a2); a3 = fmaf(w, xv.w, a3);
    }
  }
  float h[4];
  h[0] = gelu_f(a0); h[1] = gelu_f(a1); h[2] = gelu_f(a2); h[3] = gelu_f(a3);
  u16* outs[3] = {gq, gk, gv};
#pragma unroll
  for (int p = 0; p < 3; ++p) {
    const float pw = pw_w[p], pb = pw_b[p];
    float y[4];
#pragma unroll
    for (int j = 0; j < 4; ++j) y[j] = gelu_f(fmaf(h[j], pw, pb));
    uint2 o_;
    o_.x = (u32)f2bf(y[0]) | ((u32)f2bf(y[1]) << 16);
    o_.y = (u32)f2bf(y[2]) | ((u32)f2bf(y[3]) << 16);
    *(uint2*)(outs[p] + row * HDIM + lane * 4) = o_;
  }
}

// ---------------- plain MFMA GEMM (QKV via grid.z / Wo+residual) ----------------
// EPI 0: z=0,1 -> bf16 out at Outv + z*o_z; z=2 -> bf16 transposed [b][h][d][s] into vt
// EPI 1: f32 out + f32 residual
template <int EPI>
__global__ __launch_bounds__(256) void gemm_glds(
    const u16* __restrict__ A, const u16* __restrict__ BT, void* __restrict__ Outv,
    u16* __restrict__ vt, const float* __restrict__ residv, int KW, int N,
    long a_z, long b_z, long o_z) {
  __shared__ __align__(16) u16 As[128 * 64];
  __shared__ __align__(16) u16 Bs[128 * 64];
  const int tid = threadIdx.x;
  const int lane = tid & 63;
  const int wid = tid >> 6;
  const int wm = (wid & 1) * 64;
  const int wn = (wid >> 1) * 64;
  const int fm = lane & 15;
  const int fq = lane >> 4;
  const int t0 = blockIdx.x * 128;
  const int n0 = blockIdx.y * 128;
  A += (long)blockIdx.z * a_z;
  BT += (long)blockIdx.z * b_z;

  const int srow = lane >> 3;
  const int cseg = (((lane & 7) ^ srow) << 3);

  f32x4 acc[4][4];
#pragma unroll
  for (int a = 0; a < 4; ++a)
#pragma unroll
    for (int b = 0; b < 4; ++b) acc[a][b] = (f32x4){0.f, 0.f, 0.f, 0.f};

  u16* alb = &As[wid * 32 * 64];
  u16* blb = &Bs[wid * 32 * 64];

  for (int k0 = 0; k0 < KW; k0 += 64) {
    const u16* ag = A + (long)(t0 + wid * 32 + srow) * KW + k0 + cseg;
    const u16* bg = BT + (long)(n0 + wid * 32 + srow) * KW + k0 + cseg;
#pragma unroll
    for (int j = 0; j < 4; ++j) {
      glds16(ag + (long)(8 * j) * KW, alb + j * 8 * 64);
      glds16(bg + (long)(8 * j) * KW, blb + j * 8 * 64);
    }
    __syncthreads();
#pragma unroll
    for (int kk = 0; kk < 2; ++kk) {
      const int g = kk * 4 + fq;
      bf16x8 af[4], bfv[4];
#pragma unroll
      for (int t = 0; t < 4; ++t) {
        const int ra = wm + t * 16 + fm;
        af[t] = *(const bf16x8*)&As[ra * 64 + ((g ^ (ra & 7)) << 3)];
        const int rb = wn + t * 16 + fm;
        bfv[t] = *(const bf16x8*)&Bs[rb * 64 + ((g ^ (rb & 7)) << 3)];
      }
#pragma unroll
      for (int mi = 0; mi < 4; ++mi)
#pragma unroll
        for (int ni = 0; ni < 4; ++ni)
          acc[mi][ni] = __builtin_amdgcn_mfma_f32_16x16x32_bf16(af[mi], bfv[ni], acc[mi][ni], 0, 0, 0);
    }
    __syncthreads();
  }

#pragma unroll
  for (int mi = 0; mi < 4; ++mi)
#pragma unroll
    for (int ni = 0; ni < 4; ++ni) {
      if (EPI == 0 && blockIdx.z == 2) {
        // transposed store for V: [b][h][d][s]
        const int col = n0 + wn + ni * 16 + fm;
        const int hh = col >> 5, dd = col & 31;
        const long trow0 = t0 + wm + mi * 16 + fq * 4;
        const long bb = trow0 >> 12;
        const int s0 = (int)(trow0 & (S_LEN - 1));
        uint2 o_;
        o_.x = (u32)f2bf(acc[mi][ni][0]) | ((u32)f2bf(acc[mi][ni][1]) << 16);
        o_.y = (u32)f2bf(acc[mi][ni][2]) | ((u32)f2bf(acc[mi][ni][3]) << 16);
        *(uint2*)(vt + ((bb * 8 + hh) * 32 + dd) * S_LEN + s0) = o_;
      } else {
#pragma unroll
        for (int r = 0; r < 4; ++r) {
          const long trow = t0 + wm + mi * 16 + fq * 4 + r;
          const int col = n0 + wn + ni * 16 + fm;
          const float cv = acc[mi][ni][r];
          if (EPI == 0) {
            ((u16*)Outv + (long)blockIdx.z * o_z)[trow * N + col] = f2bf(cv);
          } else {
            ((float*)Outv)[trow * N + col] = cv + residv[trow * N + col];
          }
        }
      }
    }
}

// ---------------- MFMA flash attention ----------------
// Q,K: [b][s][256] bf16 (head at h*32); VT: [b][h][32][4096] bf16
// per block (c,h,b): 128 queries, key window j0=c*128-128 .. +384
__global__ __launch_bounds__(256) void attn_mfma(const u16* __restrict__ Q, const u16* __restrict__ K,
                                                 const u16* __restrict__ VT, const float* __restrict__ rel,
                                                 u16* __restrict__ CTX) {
  __shared__ __align__(16) u16 Ks[384 * 36];     // [key][dh] pitch 36
  __shared__ __align__(16) u16 VTs[32 * 388];    // [dh][key] pitch 388
  __shared__ __align__(16) u16 Ps[4][32 * 72];   // per-wave P chunk [q][key64] pitch 72
  __shared__ float bias_s[260];
  const int c = blockIdx.x, h = blockIdx.y, b = blockIdx.z;
  const int tid = threadIdx.x;
  const int lane = tid & 63, wid = tid >> 6;
  const int fm = lane & 15, fq = lane >> 4;
  const int j0 = c * 128 - 128;
  const long kvbase = ((long)b * S_LEN) * HDIM + h * 32;
  const long vtbase = (((long)b * 8 + h) * 32) * S_LEN;

  // stage K (clamped rows)
  for (int idx = tid; idx < 384 * 4; idx += 256) {
    const int jj = idx >> 2, seg = (idx & 3) * 8;
    int j = j0 + jj; j = j < 0 ? 0 : (j > S_LEN - 1 ? S_LEN - 1 : j);
    uint4 kv = *(const uint4*)(K + kvbase + (long)j * HDIM + seg);
    *(uint4*)&Ks[jj * 36 + seg] = kv;
  }
  // stage V^T (clamped col base; values at invalid keys are masked via P=0)
#pragma unroll
  for (int p = 0; p < 6; ++p) {
    const int idx = p * 256 + tid;            // 0..1535 over 32 x 48 granules
    const int d = idx / 48, seg = idx - d * 48;
    int off = j0 + seg * 8; off = off < 0 ? 0 : (off > S_LEN - 8 ? S_LEN - 8 : off);
    uint4 vv = *(const uint4*)(VT + vtbase + (long)d * S_LEN + off);
    *(uint4*)&VTs[d * 388 + seg * 8] = vv;
  }
  for (int idx = tid; idx < 257; idx += 256) bias_s[idx] = rel[idx];
  __syncthreads();

  // Q fragments direct from global: A[m=query][k=dh]
  bf16x8 aq[2];
#pragma unroll
  for (int mi = 0; mi < 2; ++mi)
    aq[mi] = *(const bf16x8*)(Q + kvbase + (long)(c * 128 + wid * 32 + mi * 16 + fm) * HDIM + fq * 8);

  const int klo = (c == 0) ? 128 : 0;
  const int khi = (c == 31) ? 255 : 383;

  float m_r[2][4], l_r[2][4];
  f32x4 acc[2][2];
#pragma unroll
  for (int mi = 0; mi < 2; ++mi)
#pragma unroll
    for (int r = 0; r < 4; ++r) { m_r[mi][r] = -1e9f; l_r[mi][r] = 0.f; }
#pragma unroll
  for (int mi = 0; mi < 2; ++mi)
#pragma unroll
    for (int nd = 0; nd < 2; ++nd) acc[mi][nd] = (f32x4){0.f, 0.f, 0.f, 0.f};

  u16* pw = &Ps[wid][0];

  for (int ch = 0; ch < 6; ++ch) {
    // QK^T: 8 MFMAs -> scores C-layout (row=q, col=key)
    f32x4 sc[2][4];
#pragma unroll
    for (int ni = 0; ni < 4; ++ni) {
      bf16x8 bk = *(const bf16x8*)&Ks[(ch * 64 + ni * 16 + fm) * 36 + fq * 8];
#pragma unroll
      for (int mi = 0; mi < 2; ++mi)
        sc[mi][ni] = __builtin_amdgcn_mfma_f32_16x16x32_bf16(aq[mi], bk, (f32x4){0.f, 0.f, 0.f, 0.f}, 0, 0, 0);
    }
    // mask + bias, chunk max
    float cm[2][4];
#pragma unroll
    for (int mi = 0; mi < 2; ++mi)
#pragma unroll
      for (int r = 0; r < 4; ++r) cm[mi][r] = -1e9f;
#pragma unroll
    for (int mi = 0; mi < 2; ++mi)
#pragma unroll
      for (int ni = 0; ni < 4; ++ni) {
        const int keyloc = ch * 64 + ni * 16 + fm;
        const bool kval = (keyloc >= klo) && (keyloc <= khi);
#pragma unroll
        for (int r = 0; r < 4; ++r) {
          const int qloc = wid * 32 + mi * 16 + fq * 4 + r;
          const int rr = keyloc - qloc;
          const bool valid = kval && (rr >= 0) && (rr <= 256);
          const int rc = valid ? rr : 0;
          float vv = sc[mi][ni][r] + bias_s[rc];
          vv = valid ? vv : -1e9f;
          sc[mi][ni][r] = vv;
          cm[mi][r] = fmaxf(cm[mi][r], vv);
        }
      }
    // cross-lane max over the 16 fm lanes
#pragma unroll
    for (int mi = 0; mi < 2; ++mi)
#pragma unroll
      for (int r = 0; r < 4; ++r) {
        float x = cm[mi][r];
        x = fmaxf(x, __shfl_xor(x, 1));
        x = fmaxf(x, __shfl_xor(x, 2));
        x = fmaxf(x, __shfl_xor(x, 4));
        x = fmaxf(x, __shfl_xor(x, 8));
        cm[mi][r] = x;
      }
    // online rescale
    float alpha[2][4];
#pragma unroll
    for (int mi = 0; mi < 2; ++mi)
#pragma unroll
      for (int r = 0; r < 4; ++r) {
        const float nm = fmaxf(m_r[mi][r], cm[mi][r]);
        alpha[mi][r] = __expf(m_r[mi][r] - nm);
        m_r[mi][r] = nm;
        l_r[mi][r] *= alpha[mi][r];
      }
#pragma unroll
    for (int mi = 0; mi < 2; ++mi)
#pragma unroll
      for (int nd = 0; nd < 2; ++nd)
#pragma unroll
        for (int r = 0; r < 4; ++r) acc[mi][nd][r] *= alpha[mi][r];
    // p = exp(sc - m), accumulate partial l, write P to LDS (A-layout)
#pragma unroll
    for (int mi = 0; mi < 2; ++mi)
#pragma unroll
      for (int ni = 0; ni < 4; ++ni)
#pragma unroll
        for (int r = 0; r < 4; ++r) {
          const float pv = __expf(sc[mi][ni][r] - m_r[mi][r]);
          l_r[mi][r] += pv;
          pw[(mi * 16 + fq * 4 + r) * 72 + ni * 16 + fm] = f2bf(pv);
        }
    // PV: 8 MFMAs
#pragma unroll
    for (int kc = 0; kc < 2; ++kc) {
      bf16x8 ap[2], bv[2];
#pragma unroll
      for (int mi = 0; mi < 2; ++mi)
        ap[mi] = *(const bf16x8*)&pw[(mi * 16 + fm) * 72 + kc * 32 + fq * 8];
#pragma unroll
      for (int nd = 0; nd < 2; ++nd)
        bv[nd] = *(const bf16x8*)&VTs[(nd * 16 + fm) * 388 + ch * 64 + kc * 32 + fq * 8];
#pragma unroll
      for (int mi = 0; mi < 2; ++mi)
#pragma unroll
        for (int nd = 0; nd < 2; ++nd)
          acc[mi][nd] = __builtin_amdgcn_mfma_f32_16x16x32_bf16(ap[mi], bv[nd], acc[mi][nd], 0, 0, 0);
    }
  }

  // reduce l across fm lanes, normalize, store ctx
  float linv[2][4];
#pragma unroll
  for (int mi = 0; mi < 2; ++mi)
#pragma unroll
    for (int r = 0; r < 4; ++r) {
      float x = l_r[mi][r];
      x += __shfl_xor(x, 1);
      x += __shfl_xor(x, 2);
      x += __shfl_xor(x, 4);
      x += __shfl_xor(x, 8);
      linv[mi][r] = 1.0f / x;
    }
#pragma unroll
  for (int mi = 0; mi < 2; ++mi)
#pragma unroll
    for (int nd = 0; nd < 2; ++nd)
#pragma unroll
      for (int r = 0; r < 4; ++r) {
        const long s = c * 128 + wid * 32 + mi * 16 + fq * 4 + r;
        CTX[((long)b * S_LEN + s) * HDIM + h * 32 + nd * 16 + fm] = f2bf(acc[mi][nd][r] * linv[mi][r]);
      }
}

// ---------------- conv MFMA GEMM: tap-shared A tile + double-buffered B ----------------
template <int EPI>
__global__ __launch_bounds__(256) void gemm_conv(
    const u16* __restrict__ Apad, const u16* __restrict__ BT, void* __restrict__ Outv,
    const float* __restrict__ bias,
    int APITCH, int SEGR, int BPITCH, int ntaps, int dil,
    int N, int OSEGR, int OGUARD, long out_z_off) {
  __shared__ __align__(16) u16 As[144 * 64];
  __shared__ __align__(16) u16 Bs2[2][128 * 64];
  const int tid = threadIdx.x;
  const int lane = tid & 63;
  const int wid = tid >> 6;
  const int wm = (wid & 1) * 64;
  const int wn = (wid >> 1) * 64;
  const int fm = lane & 15;
  const int fq = lane >> 4;
  const int t0 = blockIdx.x * 128;
  const int n0 = blockIdx.y * 128;
  const int tap0 = blockIdx.z * ntaps;

  const int seg = t0 >> 12;
  const long abase = (long)seg * SEGR + (t0 & (S_LEN - 1)) + (long)tap0 * dil;
  const int aops = (128 + (ntaps - 1) * dil + 7) >> 3;

  const int srow = lane >> 3;
  const int cseg = (((lane & 7) ^ srow) << 3);

  f32x4 acc[4][4];
#pragma unroll
  for (int a = 0; a < 4; ++a)
#pragma unroll
    for (int b = 0; b < 4; ++b) acc[a][b] = (f32x4){0.f, 0.f, 0.f, 0.f};

  for (int k0 = 0; k0 < APITCH; k0 += 64) {
    for (int op = wid; op < aops; op += 4)
      glds16(Apad + (abase + op * 8 + srow) * APITCH + k0 + cseg, &As[op * 8 * 64]);
    {
      const long bc = (long)tap0 * APITCH + k0;
#pragma unroll
      for (int j = 0; j < 4; ++j)
        glds16(BT + (long)(n0 + wid * 32 + j * 8 + srow) * BPITCH + bc + cseg,
               &Bs2[0][(wid * 32 + j * 8) * 64]);
    }
    __syncthreads();
    for (int u = 0; u < ntaps; ++u) {
      if (u + 1 < ntaps) {
        const long bc = (long)(tap0 + u + 1) * APITCH + k0;
#pragma unroll
        for (int j = 0; j < 4; ++j)
          glds16(BT + (long)(n0 + wid * 32 + j * 8 + srow) * BPITCH + bc + cseg,
                 &Bs2[(u + 1) & 1][(wid * 32 + j * 8) * 64]);
      }
      const int du = u * dil;
      const u16* bsp = Bs2[u & 1];
#pragma unroll
      for (int kk = 0; kk < 2; ++kk) {
        const int g = kk * 4 + fq;
        bf16x8 af[4], bfv[4];
#pragma unroll
        for (int t = 0; t < 4; ++t) {
          const int ra = wm + t * 16 + fm + du;
          af[t] = *(const bf16x8*)&As[ra * 64 + ((g ^ (ra & 7)) << 3)];
          const int rb = wn + t * 16 + fm;
          bfv[t] = *(const bf16x8*)&bsp[rb * 64 + ((g ^ (rb & 7)) << 3)];
        }
#pragma unroll
        for (int mi = 0; mi < 4; ++mi)
#pragma unroll
          for (int ni = 0; ni < 4; ++ni)
            acc[mi][ni] = __builtin_amdgcn_mfma_f32_16x16x32_bf16(af[mi], bfv[ni], acc[mi][ni], 0, 0, 0);
      }
      __syncthreads();
    }
  }

#pragma unroll
  for (int mi = 0; mi < 4; ++mi)
#pragma unroll
    for (int ni = 0; ni < 4; ++ni)
#pragma unroll
      for (int r = 0; r < 4; ++r) {
        const long trow = t0 + wm + mi * 16 + fq * 4 + r;
        const int col = n0 + wn + ni * 16 + fm;
        const float cv = acc[mi][ni][r];
        if (EPI == 2) {
          const long orow = (trow >> 12) * OSEGR + OGUARD + (trow & (S_LEN - 1));
          ((u16*)Outv)[orow * N + col] = f2bf(gelu_f(cv + bias[col]));
        } else {
          (((float*)Outv) + (long)blockIdx.z * out_z_off)[trow * N + col] = cv;
        }
      }
}

// ---------------- final: out = x2 + gelu(P0+P1+P2 + b2)  (f32 out) ----------------
__global__ __launch_bounds__(256) void final_kernel(const float* __restrict__ x2, const float* __restrict__ P,
                                                    const float* __restrict__ b2, float* __restrict__ out) {
  const long i4 = ((long)blockIdx.x * 256 + threadIdx.x) * 4;
  const int c0 = (int)(i4 & (HDIM - 1));
  float4 xa = *(const float4*)(x2 + i4);
  float4 p0 = *(const float4*)(P + i4);
  float4 p1 = *(const float4*)(P + 4194304 + i4);
  float4 p2 = *(const float4*)(P + 8388608 + i4);
  const float pv[4] = {p0.x + p1.x + p2.x, p0.y + p1.y + p2.y, p0.z + p1.z + p2.z, p0.w + p1.w + p2.w};
  float4 o_;
  o_.x = xa.x + gelu_f(pv[0] + b2[c0 + 0]);
  o_.y = xa.y + gelu_f(pv[1] + b2[c0 + 1]);
  o_.z = xa.z + gelu_f(pv[2] + b2[c0 + 2]);
  o_.w = xa.w + gelu_f(pv[3] + b2[c0 + 3]);
  *(float4*)(out + i4) = o_;
}

extern "C" void kernel_launch(void* const* d_in, const int* in_sizes, int n_in,
                              void* d_out, int out_size, void* d_ws, size_t ws_size,
                              hipStream_t stream) {
  (void)in_sizes; (void)n_in; (void)out_size;
  const float* X    = (const float*)d_in[0];
  const float* dw_w = (const float*)d_in[1];
  const float* dw_b = (const float*)d_in[2];
  const float* pw_w = (const float*)d_in[3];
  const float* pw_b = (const float*)d_in[4];
  const float* Wq   = (const float*)d_in[5];
  const float* Wk   = (const float*)d_in[6];
  const float* Wv   = (const float*)d_in[7];
  const float* Wo   = (const float*)d_in[8];
  const float* rel  = (const float*)d_in[9];
  const float* ln1g = (const float*)d_in[10];
  const float* ln1b = (const float*)d_in[11];
  const float* ln2g = (const float*)d_in[12];
  const float* ln2b = (const float*)d_in[13];
  const float* w1   = (const float*)d_in[14];
  const float* b1   = (const float*)d_in[15];
  const float* w2   = (const float*)d_in[16];
  const float* b2   = (const float*)d_in[17];

  if (ws_size < 119537664) return;

  char* ws = (char*)d_ws;
  u16* WqT = (u16*)(ws + 0);
  u16* WkT = (u16*)(ws + 131072);
  u16* WvT = (u16*)(ws + 262144);
  u16* WoT = (u16*)(ws + 393216);
  u16* W1T = (u16*)(ws + 524288);
  u16* W2T = (u16*)(ws + 5242880);
  float* xn  = (float*)(ws + 10485760);   // 16 MiB, reused as x2
  float* x2  = xn;
  u16* gq  = (u16*)(ws + 27262976);
  u16* gk  = (u16*)(ws + 35651584);
  u16* gv  = (u16*)(ws + 44040192);
  u16* q   = (u16*)(ws + 52428800);       // q,k contiguous (o_z = 4M elems)
  u16* vt  = (u16*)(ws + 69206016);       // V^T [b][h][32][4096]
  u16* ctx = (u16*)(ws + 77594624);
  // phase-2 overlays (valid only after attn + Wo done)
  u16* f1p  = (u16*)(ws + 27262976);
  u16* xn2p = (u16*)(ws + 61341696);
  float* P  = (float*)(ws + 61341696);

  const float qscale = 0.17677669529663687f;
  dim3 tb(32, 8);
  ktranspose<<<dim3(8, 8), tb, 0, stream>>>(Wq, WqT, 256, 256, qscale);
  ktranspose<<<dim3(8, 8), tb, 0, stream>>>(Wk, WkT, 256, 256, 1.0f);
  ktranspose<<<dim3(8, 8), tb, 0, stream>>>(Wv, WvT, 256, 256, 1.0f);
  ktranspose<<<dim3(8, 8), tb, 0, stream>>>(Wo, WoT, 256, 256, 1.0f);
  ktranspose<<<dim3(72, 32), tb, 0, stream>>>(w1, W1T, 2304, 1024, 1.0f);
  ktranspose<<<dim3(288, 8), tb, 0, stream>>>(w2, W2T, 9216, 256, 1.0f);

  ln_kernel<0><<<4096, 256, 0, stream>>>(X, xn, ln1g, ln1b, 4096, 0);
  dwconv_qkv<<<4096, 256, 0, stream>>>(xn, gq, gk, gv, dw_w, dw_b, pw_w, pw_b);

  gemm_glds<0><<<dim3(128, 2, 3), 256, 0, stream>>>(gq, WqT, q, vt, nullptr,
      256, 256, 4194304, 65536, 4194304);

  attn_mfma<<<dim3(32, 8, 4), 256, 0, stream>>>(q, q + 4194304, vt, rel, ctx);

  gemm_glds<1><<<dim3(128, 2), 256, 0, stream>>>(ctx, WoT, x2, nullptr, X, 256, 256, 0, 0, 0);

  zero_guards<<<132, 256, 0, stream>>>((uint4*)xn2p, (uint4*)f1p);

  ln_kernel<1><<<4096, 256, 0, stream>>>(x2, xn2p, ln2g, ln2b, 4104, 8);

  gemm_conv<2><<<dim3(128, 8), 256, 0, stream>>>(xn2p, W1T, f1p, b1,
      256, 4104, 2304, 9, 1, 1024, 4160, 64, 0);

  gemm_conv<3><<<dim3(128, 2, 3), 256, 0, stream>>>(f1p, W2T, P, nullptr,
      1024, 4160, 9216, 3, 8, 256, 0, 0, 4194304);

  final_kernel<<<4096, 256, 0, stream>>>(x2, P, b2, (float*)d_out);
}